// Round 13
// baseline (275.185 us; speedup 1.0000x reference)
//
#include <hip/hip_runtime.h>
#include <hip/hip_bf16.h>

#define DEV static __device__ __forceinline__

constexpr int T_ = 2048, DIM_ = 2048, H_ = 16, KVH = 4, D_ = 128;
constexpr int LL = 32, SS = 16, TOPK_ = 16, WIN_ = 512;
constexpr int GATE_HID_ = 512;
constexpr int TC_ = 127, NS_ = 32;
constexpr int QKV_N = (H_ + 2 * KVH) * D_;          // 3072
constexpr float SCALE_ = 0.08838834764831845f;       // D^-0.5

typedef __attribute__((ext_vector_type(8))) short short8;
typedef __attribute__((ext_vector_type(4))) float f32x4;
typedef __attribute__((ext_vector_type(4))) float float4v;
typedef __attribute__((ext_vector_type(4))) unsigned short u16x4;

DEV unsigned short f2b(float x) {
    return __builtin_bit_cast(unsigned short, __float2bfloat16(x));
}
DEV float b2f(unsigned short u) { return __builtin_bit_cast(float, ((unsigned)u) << 16); }
DEV float gelu_f(float x) { return 0.5f * x * (1.f + erff(x * 0.70710678118654752f)); }

DEV void g2l16(const void* g, void* l) {
    __builtin_amdgcn_global_load_lds((const __attribute__((address_space(1))) unsigned int*)g,
                                     (__attribute__((address_space(3))) unsigned int*)l, 16, 0, 0);
}

// ---------------------------------------------------------------------------
// f32 -> bf16 conversion (vectorized), n divisible by 4
// ---------------------------------------------------------------------------
__global__ void cvt_f2b(const float* __restrict__ s, unsigned short* __restrict__ d, int n) {
    const int i = (blockIdx.x * 256 + threadIdx.x) * 4;
    if (i >= n) return;
    float4v v = *(const float4v*)(s + i);
    u16x4 o;
#pragma unroll
    for (int j = 0; j < 4; j++) o[j] = f2b(v[j]);
    *(u16x4*)(d + i) = o;
}

// ---------------------------------------------------------------------------
// Fused conversion of x, W_qkv, W_g1, W_c1, W_c2 (one launch)
// ---------------------------------------------------------------------------
__global__ void cvt_all(const float* __restrict__ x, const float* __restrict__ wq,
                        const float* __restrict__ wg, const float* __restrict__ wc1,
                        const float* __restrict__ wc2,
                        unsigned short* __restrict__ xb, unsigned short* __restrict__ wqb,
                        unsigned short* __restrict__ wgb, unsigned short* __restrict__ wc1b,
                        unsigned short* __restrict__ wc2b) {
    const long i = ((long)blockIdx.x * 256 + threadIdx.x) * 4;
    const float* s;
    unsigned short* d;
    long off;
    if (i < 4194304)        { s = x;   d = xb;   off = i; }
    else if (i < 10485760)  { s = wq;  d = wqb;  off = i - 4194304; }
    else if (i < 11534336)  { s = wg;  d = wgb;  off = i - 10485760; }
    else if (i < 12582912)  { s = wc1; d = wc1b; off = i - 11534336; }
    else if (i < 12615680)  { s = wc2; d = wc2b; off = i - 12582912; }
    else return;
    float4v v = *(const float4v*)(s + off);
    u16x4 o;
#pragma unroll
    for (int j = 0; j < 4; j++) o[j] = f2b(v[j]);
    *(u16x4*)(d + off) = o;
}

// ---------------------------------------------------------------------------
// BK=64 GEMM building blocks: swizzled g2l16 staging + matching ds_read XOR.
// ---------------------------------------------------------------------------
DEV void stage64(const unsigned short* __restrict__ src, unsigned short* dstL,
                 int K, int tid) {        // 128 rows
#pragma unroll
    for (int it = 0; it < 4; it++) {
        const int e = it * 256 + tid;          // 16B-chunk index, 0..1023
        const int row = e >> 3, cg = e & 7;
        g2l16(src + (size_t)row * K + ((cg ^ (row & 7)) << 3), dstL + e * 8);
    }
}
DEV void stageA64(const unsigned short* __restrict__ src, unsigned short* dstL,
                  int K, int tid) {       // 64 rows
#pragma unroll
    for (int it = 0; it < 2; it++) {
        const int e = it * 256 + tid;          // 0..511
        const int row = e >> 3, cg = e & 7;
        g2l16(src + (size_t)row * K + ((cg ^ (row & 7)) << 3), dstL + e * 8);
    }
}
DEV short8 frag64(const unsigned short* Ls, int row, int g) {   // g = ks*4+lg
    return *(const short8*)&Ls[row * 64 + ((g ^ (row & 7)) << 3)];
}

// ---------------------------------------------------------------------------
// bf16 GEMM, 64x128 tile (BK=64): C = A @ B^T + bias.
// ---------------------------------------------------------------------------
template <int ACT, bool WF, bool WB>
__global__ __launch_bounds__(256) void gemm64(const unsigned short* __restrict__ A,
                                              const unsigned short* __restrict__ B,
                                              const float* __restrict__ bias,
                                              float* __restrict__ Cf,
                                              unsigned short* __restrict__ Cb,
                                              int M, int N, int K) {
    __shared__ __align__(16) unsigned short As[64 * 64];
    __shared__ __align__(16) unsigned short Bs[128 * 64];
    const int tid = threadIdx.x;
    const int w = tid >> 6, l = tid & 63;
    const int lc = l & 15, lg = l >> 4;
    const int m0 = blockIdx.y * 64, n0 = blockIdx.x * 128;
    f32x4 acc[4][2] = {};
    for (int k0 = 0; k0 < K; k0 += 64) {
        stageA64(A + (size_t)m0 * K + k0, As, K, tid);
        stage64(B + (size_t)n0 * K + k0, Bs, K, tid);
        __syncthreads();
#pragma unroll
        for (int ks = 0; ks < 2; ks++) {
            short8 af[4], bfr[2];
#pragma unroll
            for (int mi = 0; mi < 4; mi++) af[mi] = frag64(As, mi * 16 + lc, ks * 4 + lg);
#pragma unroll
            for (int ni = 0; ni < 2; ni++) bfr[ni] = frag64(Bs, w * 32 + ni * 16 + lc, ks * 4 + lg);
#pragma unroll
            for (int mi = 0; mi < 4; mi++)
#pragma unroll
                for (int ni = 0; ni < 2; ni++)
                    acc[mi][ni] = __builtin_amdgcn_mfma_f32_16x16x32_bf16(af[mi], bfr[ni], acc[mi][ni], 0, 0, 0);
        }
        __syncthreads();
    }
#pragma unroll
    for (int mi = 0; mi < 4; mi++) {
        const int gr = m0 + mi * 16 + lg * 4;
#pragma unroll
        for (int ni = 0; ni < 2; ni++) {
            const int gc = n0 + w * 32 + ni * 16 + lc;
            const float bv = bias[gc];
#pragma unroll
            for (int r = 0; r < 4; r++) {
                float v = acc[mi][ni][r] + bv;
                if (ACT == 1) v = gelu_f(v);
                const size_t idx = (size_t)(gr + r) * N + gc;
                if (WF) Cf[idx] = v;
                if (WB) Cb[idx] = f2b(v);
            }
        }
    }
}

// ---------------------------------------------------------------------------
// Fused qkv + gate-hidden GEMM, 64x128 tile
// ---------------------------------------------------------------------------
__global__ __launch_bounds__(256) void gemm_qkvg(const unsigned short* __restrict__ A,
                                                 const unsigned short* __restrict__ Bq,
                                                 const unsigned short* __restrict__ Bg,
                                                 const float* __restrict__ bq,
                                                 const float* __restrict__ bg,
                                                 unsigned short* __restrict__ Cq,
                                                 float* __restrict__ Cg) {
    __shared__ __align__(16) unsigned short As[64 * 64];
    __shared__ __align__(16) unsigned short Bs[128 * 64];
    const int K = DIM_;
    const int tid = threadIdx.x;
    const int w = tid >> 6, l = tid & 63;
    const int lc = l & 15, lg = l >> 4;
    const int m0 = blockIdx.y * 64, n0 = blockIdx.x * 128;
    const bool isg = (n0 >= QKV_N);
    const unsigned short* B = isg ? (Bg + (size_t)(n0 - QKV_N) * K) : (Bq + (size_t)n0 * K);
    f32x4 acc[4][2] = {};
    for (int k0 = 0; k0 < K; k0 += 64) {
        stageA64(A + (size_t)m0 * K + k0, As, K, tid);
        stage64(B + k0, Bs, K, tid);
        __syncthreads();
#pragma unroll
        for (int ks = 0; ks < 2; ks++) {
            short8 af[4], bfr[2];
#pragma unroll
            for (int mi = 0; mi < 4; mi++) af[mi] = frag64(As, mi * 16 + lc, ks * 4 + lg);
#pragma unroll
            for (int ni = 0; ni < 2; ni++) bfr[ni] = frag64(Bs, w * 32 + ni * 16 + lc, ks * 4 + lg);
#pragma unroll
            for (int mi = 0; mi < 4; mi++)
#pragma unroll
                for (int ni = 0; ni < 2; ni++)
                    acc[mi][ni] = __builtin_amdgcn_mfma_f32_16x16x32_bf16(af[mi], bfr[ni], acc[mi][ni], 0, 0, 0);
        }
        __syncthreads();
    }
#pragma unroll
    for (int mi = 0; mi < 4; mi++) {
        const int gr = m0 + mi * 16 + lg * 4;
#pragma unroll
        for (int ni = 0; ni < 2; ni++) {
            const int gcl = (n0 - (isg ? QKV_N : 0)) + w * 32 + ni * 16 + lc;
            const float bv = isg ? bg[gcl] : bq[gcl];
#pragma unroll
            for (int r = 0; r < 4; r++) {
                const float v = acc[mi][ni][r] + bv;
                if (isg) Cg[(size_t)(gr + r) * GATE_HID_ + gcl] = gelu_f(v);
                else Cq[(size_t)(gr + r) * QKV_N + gcl] = f2b(v);
            }
        }
    }
}

// ---------------------------------------------------------------------------
// c1 GEMM, split-K partials, 64x128 tile
// ---------------------------------------------------------------------------
__global__ __launch_bounds__(256) void gemm_c1p(const unsigned short* __restrict__ A,
                                                const unsigned short* __restrict__ B,
                                                float* __restrict__ part) {
    __shared__ __align__(16) unsigned short As[64 * 64];
    __shared__ __align__(16) unsigned short Bs[128 * 64];
    const int K = 4096, N = 256;
    const int tid = threadIdx.x;
    const int w = tid >> 6, l = tid & 63;
    const int lc = l & 15, lg = l >> 4;
    const int m0 = blockIdx.y * 64, n0 = blockIdx.x * 128;
    const int kz = blockIdx.z * 1024;
    f32x4 acc[4][2] = {};
    for (int k0 = kz; k0 < kz + 1024; k0 += 64) {
        stageA64(A + (size_t)m0 * K + k0, As, K, tid);
        stage64(B + (size_t)n0 * K + k0, Bs, K, tid);
        __syncthreads();
#pragma unroll
        for (int ks = 0; ks < 2; ks++) {
            short8 af[4], bfr[2];
#pragma unroll
            for (int mi = 0; mi < 4; mi++) af[mi] = frag64(As, mi * 16 + lc, ks * 4 + lg);
#pragma unroll
            for (int ni = 0; ni < 2; ni++) bfr[ni] = frag64(Bs, w * 32 + ni * 16 + lc, ks * 4 + lg);
#pragma unroll
            for (int mi = 0; mi < 4; mi++)
#pragma unroll
                for (int ni = 0; ni < 2; ni++)
                    acc[mi][ni] = __builtin_amdgcn_mfma_f32_16x16x32_bf16(af[mi], bfr[ni], acc[mi][ni], 0, 0, 0);
        }
        __syncthreads();
    }
    float* dst = part + (size_t)blockIdx.z * 2048 * 256;
#pragma unroll
    for (int mi = 0; mi < 4; mi++) {
        const int gr = m0 + mi * 16 + lg * 4;
#pragma unroll
        for (int ni = 0; ni < 2; ni++) {
            const int gc = n0 + w * 32 + ni * 16 + lc;
#pragma unroll
            for (int r = 0; r < 4; r++) dst[(size_t)(gr + r) * N + gc] = acc[mi][ni][r];
        }
    }
}

// ---------------------------------------------------------------------------
// reduce c1 partials + bias + gelu -> bf16
// ---------------------------------------------------------------------------
__global__ void c1_red(const float* __restrict__ part, const float* __restrict__ bias,
                       unsigned short* __restrict__ out) {
    const int i4 = blockIdx.x * 256 + threadIdx.x;   // 131072
    const int base = i4 * 4;
    const int col = base & 255;
    float4v v = *(const float4v*)(part + base);
#pragma unroll
    for (int z = 1; z < 4; z++) {
        float4v p = *(const float4v*)(part + (size_t)z * 524288 + base);
#pragma unroll
        for (int j = 0; j < 4; j++) v[j] += p[j];
    }
    u16x4 o;
#pragma unroll
    for (int j = 0; j < 4; j++) o[j] = f2b(gelu_f(v[j] + bias[col + j]));
    *(u16x4*)(out + base) = o;
}

// ---------------------------------------------------------------------------
// c2 GEMM, 64x128 tile: hcmp = hc @ Wc2^T + b; also emits vcmpT[kv][d][c]
// ---------------------------------------------------------------------------
__global__ __launch_bounds__(256) void gemm_c2(const unsigned short* __restrict__ A,
                                               const unsigned short* __restrict__ B,
                                               const float* __restrict__ bias,
                                               unsigned short* __restrict__ Cb,
                                               unsigned short* __restrict__ vcmpT) {
    __shared__ __align__(16) unsigned short As[64 * 64];
    __shared__ __align__(16) unsigned short Bs[128 * 64];
    const int K = 256, N = 128;
    const int tid = threadIdx.x;
    const int w = tid >> 6, l = tid & 63;
    const int lc = l & 15, lg = l >> 4;
    const int m0 = blockIdx.y * 64;
    f32x4 acc[4][2] = {};
    for (int k0 = 0; k0 < K; k0 += 64) {
        stageA64(A + (size_t)m0 * K + k0, As, K, tid);
        stage64(B + k0, Bs, K, tid);
        __syncthreads();
#pragma unroll
        for (int ks = 0; ks < 2; ks++) {
            short8 af[4], bfr[2];
#pragma unroll
            for (int mi = 0; mi < 4; mi++) af[mi] = frag64(As, mi * 16 + lc, ks * 4 + lg);
#pragma unroll
            for (int ni = 0; ni < 2; ni++) bfr[ni] = frag64(Bs, w * 32 + ni * 16 + lc, ks * 4 + lg);
#pragma unroll
            for (int mi = 0; mi < 4; mi++)
#pragma unroll
                for (int ni = 0; ni < 2; ni++)
                    acc[mi][ni] = __builtin_amdgcn_mfma_f32_16x16x32_bf16(af[mi], bfr[ni], acc[mi][ni], 0, 0, 0);
        }
        __syncthreads();
    }
#pragma unroll
    for (int mi = 0; mi < 4; mi++) {
        const int gr = m0 + mi * 16 + lg * 4;
#pragma unroll
        for (int ni = 0; ni < 2; ni++) {
            const int gc = w * 32 + ni * 16 + lc;
            const float bv = bias[gc];
#pragma unroll
            for (int r = 0; r < 4; r++) {
                const int row = gr + r;
                const float v = acc[mi][ni][r] + bv;
                const unsigned short bv16 = f2b(v);
                Cb[(size_t)row * N + gc] = bv16;
                if (row >= 1024) {
                    const int mm = row - 1024;
                    const int cc = mm >> 2, kvv = mm & 3;
                    if (cc < 128) vcmpT[((size_t)(kvv * 128 + gc)) * 128 + cc] = bv16;
                }
            }
        }
    }
}

// ---------------------------------------------------------------------------
// Fused post-qkv kernel: [0,128) transp_kv | [128,1664) gate2 | [1664,3712) blk_build
// ---------------------------------------------------------------------------
__global__ __launch_bounds__(256) void post_qkv(const unsigned short* __restrict__ qkvb,
                                                const float* __restrict__ cmp_pos,
                                                const float* __restrict__ hg,
                                                const float* __restrict__ Wg2,
                                                const float* __restrict__ bg2,
                                                unsigned short* __restrict__ kvTs,
                                                float* __restrict__ gate,
                                                unsigned short* __restrict__ blk) {
    const int bb = blockIdx.x;
    const int tid = threadIdx.x;
    if (bb < 128) {
        const int kv = bb & 3, tb = bb >> 2;
        const int t0 = tb * 64;
        unsigned short* dstK = kvTs + (size_t)(kv * 32 + tb) * 16384;
        unsigned short* dstV = dstK + 8192;
        const int kcol0 = H_ * D_ + kv * D_;
        const int vcol0 = H_ * D_ + KVH * D_ + kv * D_;
#pragma unroll
        for (int it = 0; it < 4; it++) {
            const int c = it * 256 + tid;
            const int key = c >> 4, g = c & 15;
            short8 v = *(const short8*)(qkvb + (size_t)(t0 + key) * QKV_N + kcol0 + g * 8);
            *(short8*)(dstK + key * 128 + ((g ^ (key & 7)) << 3)) = v;
        }
        __shared__ __align__(16) unsigned short tile[64][136];
        const int rr = tid >> 4, d0 = (tid & 15) * 8;
#pragma unroll
        for (int mIt = 0; mIt < 4; mIt++) {
            const int row = rr + mIt * 16;
            *(short8*)&tile[row][d0] = *(const short8*)(qkvb + (size_t)(t0 + row) * QKV_N + vcol0 + d0);
        }
        __syncthreads();
        const int d = tid >> 1, half = tid & 1;
        unsigned short* dv = dstV + d * 64;
#pragma unroll
        for (int c2 = 0; c2 < 4; c2++) {
            const int g = half * 4 + c2;
            short8 v;
#pragma unroll
            for (int j = 0; j < 8; j++) v[j] = tile[g * 8 + j][d];
            *(short8*)(dv + ((g ^ (d & 7)) << 3)) = v;
        }
    } else if (bb < 1664) {
        const int gi = (bb - 128) * 4 + (tid >> 6);
        const int t = gi / 3, i = gi % 3;
        const int l = tid & 63;
        const float* h = hg + (size_t)t * GATE_HID_;
        const float* w = Wg2 + (size_t)i * GATE_HID_;
        float s = 0.f;
#pragma unroll
        for (int j = 0; j < GATE_HID_ / 64; j++) s += h[l + j * 64] * w[l + j * 64];
#pragma unroll
        for (int o = 32; o > 0; o >>= 1) s += __shfl_xor(s, o);
        if (l == 0) gate[gi] = 1.f / (1.f + expf(-(s + bg2[i])));
    } else {
        const int b = bb - 1664;                 // 0..2047
        const int which = b >> 10, m = b & 1023;
        unsigned short* dst = blk + ((size_t)(which * 1024 + m)) * (LL * D_);
        if (m >= TC_ * KVH) {
            short8 z = {};
#pragma unroll
            for (int it = 0; it < 2; it++) *(short8*)(dst + (tid + it * 256) * 8) = z;
            return;
        }
        const int c = m >> 2, kv = m & 3;
        const int col0 = H_ * D_ + which * KVH * D_ + kv * D_;
#pragma unroll
        for (int it = 0; it < 2; it++) {
            const int g = tid + it * 256;
            const int lrow = g >> 4, d0 = (g & 15) * 8;
            short8 z = *(const short8*)(qkvb + (size_t)(c * SS + lrow) * QKV_N + col0 + d0);
            float4v p0 = *(const float4v*)(cmp_pos + lrow * 128 + d0);
            float4v p1 = *(const float4v*)(cmp_pos + lrow * 128 + d0 + 4);
            short8 o;
#pragma unroll
            for (int j = 0; j < 4; j++) o[j] = (short)f2b(b2f((unsigned short)z[j]) + p0[j]);
#pragma unroll
            for (int j = 0; j < 4; j++) o[4 + j] = (short)f2b(b2f((unsigned short)z[4 + j]) + p1[j]);
            *(short8*)(dst + g * 8) = o;
        }
    }
}

// ---------------------------------------------------------------------------
// CMP attention (MFMA) + block-score slices; V^T direct from L2 (vcmpT)
// ---------------------------------------------------------------------------
__global__ __launch_bounds__(256) void cmp_attn2(const unsigned short* __restrict__ qkvb,
                                                 const unsigned short* __restrict__ kcmpb,
                                                 const unsigned short* __restrict__ vcmpT,
                                                 const float* __restrict__ gate,
                                                 float* __restrict__ obuf,
                                                 float* __restrict__ scg) {
    const int bid = blockIdx.x;               // 512 blocks
    const int kv = bid & 3;
    const int tx = bid >> 2;                  // 0..127
    const int tt = (tx & 1) ? (tx >> 1) : (127 - (tx >> 1));
    const int t0 = tt * 16;
    const int tid = threadIdx.x;
    const int w = tid >> 6, l = tid & 63;
    const int lc = l & 15, lg = l >> 4;
    const int h = kv * 4 + w;

    __shared__ float pbuf[4][16][132];

    short8 aq[4];
    {
        const unsigned short* qp = qkvb + (size_t)(t0 + lc) * QKV_N + h * D_ + lg * 8;
#pragma unroll
        for (int ks = 0; ks < 4; ks++) aq[ks] = *(const short8*)(qp + ks * 32);
    }

    f32x4 sfr[8] = {};
#pragma unroll
    for (int nj = 0; nj < 8; nj++) {
        const int c = nj * 16 + lc;
        const unsigned short* kp = kcmpb + ((size_t)(c * 4 + kv)) * D_ + lg * 8;
#pragma unroll
        for (int ks = 0; ks < 4; ks++) {
            short8 bf = *(const short8*)(kp + ks * 32);
            sfr[nj] = __builtin_amdgcn_mfma_f32_16x16x32_bf16(aq[ks], bf, sfr[nj], 0, 0, 0);
        }
    }

#pragma unroll
    for (int r = 0; r < 4; r++) {
        const int t = t0 + lg * 4 + r;
        const int nv = (t >= LL - 1) ? ((t - (LL - 1)) >> 4) + 1 : 0;
        float lv[8], mx = -1e30f;
#pragma unroll
        for (int nj = 0; nj < 8; nj++) {
            const int c = nj * 16 + lc;
            const float v = (c < nv) ? sfr[nj][r] * SCALE_ : -1e30f;
            lv[nj] = v;
            mx = fmaxf(mx, v);
        }
#pragma unroll
        for (int o = 1; o < 16; o <<= 1) mx = fmaxf(mx, __shfl_xor(mx, o));
        float s = 0.f, pe[8];
#pragma unroll
        for (int nj = 0; nj < 8; nj++) {
            const float e = (lv[nj] > -1e29f) ? __expf(lv[nj] - mx) : 0.f;
            pe[nj] = e;
            s += e;
        }
#pragma unroll
        for (int o = 1; o < 16; o <<= 1) s += __shfl_xor(s, o);
        const float inv = (s > 0.f) ? 1.f / s : 0.f;
#pragma unroll
        for (int nj = 0; nj < 8; nj++) sfr[nj][r] = pe[nj] * inv;
    }

#pragma unroll
    for (int nj = 0; nj < 8; nj++)
#pragma unroll
        for (int r = 0; r < 4; r++) pbuf[w][lg * 4 + r][nj * 16 + lc] = sfr[nj][r];

    __syncthreads();

    for (int idx = tid; idx < 16 * NS_; idx += 256) {
        const int lt = idx >> 5, j = idx & 31;
        int clo = 4 * j - 1;
        if (clo < 0) clo = 0;
        const int chi = 4 * j + 3;
        float s = 0.f;
        for (int c = clo; c <= chi; c++)
            s += pbuf[0][lt][c] + pbuf[1][lt][c] + pbuf[2][lt][c] + pbuf[3][lt][c];
        scg[((size_t)kv * T_ + (t0 + lt)) * NS_ + j] = s;
    }

    short8 pa[4];
#pragma unroll
    for (int ks = 0; ks < 4; ks++) {
        const float* pr = &pbuf[w][lc][ks * 32 + lg * 8];
        short8 t;
#pragma unroll
        for (int j = 0; j < 8; j++) t[j] = (short)f2b(pr[j]);
        pa[ks] = t;
    }
    f32x4 acc[8] = {};
#pragma unroll
    for (int nj = 0; nj < 8; nj++) {
        const int dd = nj * 16 + lc;
        const unsigned short* vp = vcmpT + ((size_t)(kv * 128 + dd)) * 128 + lg * 8;
#pragma unroll
        for (int ks = 0; ks < 4; ks++) {
            short8 bf = *(const short8*)(vp + ks * 32);
            acc[nj] = __builtin_amdgcn_mfma_f32_16x16x32_bf16(pa[ks], bf, acc[nj], 0, 0, 0);
        }
    }

#pragma unroll
    for (int r = 0; r < 4; r++) {
        const int t = t0 + lg * 4 + r;
        const float g0 = gate[t * 3 + 0];
#pragma unroll
        for (int nj = 0; nj < 8; nj++)
            obuf[(size_t)t * (H_ * D_) + h * D_ + nj * 16 + lc] = g0 * acc[nj][r];
    }
}

// ---------------------------------------------------------------------------
// top-k block selection -> bitmask
// ---------------------------------------------------------------------------
__global__ __launch_bounds__(256) void topk_k(const float* __restrict__ scg,
                                              unsigned int* __restrict__ amask) {
    const int t = blockIdx.x * 256 + threadIdx.x;
    if (t >= T_) return;
    float sc[NS_];
#pragma unroll
    for (int j = 0; j < NS_; j++)
        sc[j] = scg[((size_t)0 * T_ + t) * NS_ + j] + scg[((size_t)1 * T_ + t) * NS_ + j] +
                scg[((size_t)2 * T_ + t) * NS_ + j] + scg[((size_t)3 * T_ + t) * NS_ + j];
    const int cur = t >> 6;
    unsigned int chosen = 0;
    for (int it = 0; it < TOPK_ - 3; it++) {
        float best = 0.f;
        int bj = -1;
        for (int j = 0; j < NS_; j++) {
            if ((chosen >> j) & 1u) continue;
            const float v = (j >= cur) ? -INFINITY : sc[j];
            if (bj < 0 || v > best) { best = v; bj = j; }
        }
        chosen |= 1u << bj;
    }
    int f1 = cur - 2; if (f1 < 0) f1 = 0;
    int f2 = cur - 1; if (f2 < 0) f2 = 0;
    chosen |= 1u | (1u << f1) | (1u << f2) | (1u << cur);
    amask[t] = chosen;
}

// ---------------------------------------------------------------------------
// helpers for slc_swa_pt
// ---------------------------------------------------------------------------
DEV void write_P(unsigned short* PsW, const float p[4][4], int lc, int lg) {
#pragma unroll
    for (int kt = 0; kt < 4; kt++) {
        const int col = kt * 16 + lc;
#pragma unroll
        for (int rp = 0; rp < 4; rp += 2) {
            unsigned int pk;
            asm("v_cvt_pk_bf16_f32 %0, %1, %2" : "=v"(pk) : "v"(p[kt][rp]), "v"(p[kt][rp + 1]));
            const int row0 = lg * 4 + rp;
            const int row1 = row0 + 1;
            PsW[row0 * 64 + (col ^ ((row0 & 7) << 3))] = (unsigned short)(pk & 0xFFFFu);
            PsW[row1 * 64 + (col ^ ((row1 & 7) << 3))] = (unsigned short)(pk >> 16);
        }
    }
}

DEV void stageKV(const unsigned short* __restrict__ src, unsigned short* dst, int tid) {
#pragma unroll
    for (int it = 0; it < 8; it++) {
        const int c = it * 256 + tid;          // 16B chunk index, 0..2047
        g2l16(src + c * 8, dst + c * 8);
    }
}

// ---------------------------------------------------------------------------
// SLC+SWA partial kernel v9: single-buffered KV + MERGED PV (each V fragment
// read once, feeds both streams). Ps[wave][2 streams]. LDS 48KB -> 3 blk/CU.
// 1024 blocks (qb heaviest first).
// ---------------------------------------------------------------------------
__global__ __launch_bounds__(256) void slc_swa_pt(const unsigned short* __restrict__ qkvb,
                                                  const unsigned short* __restrict__ kvTs,
                                                  const unsigned int* __restrict__ amask,
                                                  float* __restrict__ mlp,
                                                  unsigned short* __restrict__ accp) {
    const int bid = blockIdx.x;               // 1024 blocks
    const int qb = 31 - (bid >> 5);           // heaviest first
    const int hs = bid & 31;
    const int h = hs >> 1, seg = hs & 1;
    const int kv = h >> 2;
    const int tid = threadIdx.x;
    const int w = tid >> 6, l = tid & 63;
    const int lc = l & 15, lg = l >> 4;
    const int t0 = qb * 64;
    const int cur = qb;

    __shared__ __align__(16) unsigned short KV[16384];   // [K 8192 | V 8192]
    __shared__ __align__(16) unsigned short Ps[4][2][1024];

    const short8 ones = {0x3F80, 0x3F80, 0x3F80, 0x3F80, 0x3F80, 0x3F80, 0x3F80, 0x3F80};

    // masks fully in registers
    const unsigned int aml = amask[t0 + l];
    unsigned int u64v = aml;
#pragma unroll
    for (int o = 1; o < 64; o <<= 1) u64v |= __shfl_xor(u64v, o);
    unsigned int u16g = aml;
#pragma unroll
    for (int o = 1; o < 16; o <<= 1) u16g |= __shfl_xor(u16g, o);
    const unsigned int uni16 = __shfl(u16g, w * 16);
    unsigned int amr[4];
    int tq[4];
#pragma unroll
    for (int r = 0; r < 4; r++) {
        const int rl = w * 16 + lg * 4 + r;
        tq[r] = t0 + rl;
        amr[r] = __shfl(aml, rl);
    }
    const int tmin_w = t0 + w * 16;
    const int tmax_w = tmin_w + 15;

    const unsigned int curm = (cur >= 31) ? 0xFFFFFFFFu : ((1u << (cur + 1)) - 1u);
    int sl = qb - 8; if (sl < 0) sl = 0;
    const unsigned int swab = curm & ~((1u << sl) - 1u);
    const unsigned int act = (u64v & curm) | swab;
    unsigned int actseg = 0;
    {
        int rank = 0;
        for (int jb = 0; jb <= cur; jb++)
            if ((act >> jb) & 1u) {
                if ((rank & 1) == seg) actseg |= 1u << jb;
                rank++;
            }
    }

    short8 aq[4];
    {
        const unsigned short* qp = qkvb + (size_t)(t0 + w * 16 + lc) * QKV_N + h * D_ + lg * 8;
#pragma unroll
        for (int ks = 0; ks < 4; ks++) aq[ks] = *(const short8*)(qp + ks * 32);
    }

    f32x4 acc_s[8] = {};
    f32x4 acc_w[8] = {};
    f32x4 ls4 = {}, lw4 = {};
    float m[4];
#pragma unroll
    for (int r = 0; r < 4; r++) m[r] = -1e30f;

    const unsigned short* kvbase = kvTs + (size_t)kv * 32 * 16384;

    unsigned int rem = actseg;
    while (rem) {
        const int jb = __ffs(rem) - 1;
        rem &= rem - 1;
        stageKV(kvbase + (size_t)jb * 16384, KV, tid);
        __syncthreads();   // KV(jb) staged
        const bool slc_w = (uni16 >> jb) & 1u;
        const bool swa_w = (jb * 64 + 63) > (tmin_w - WIN_);
        if (slc_w || swa_w) {
            const unsigned short* Kb = KV;
            const unsigned short* Vb = KV + 8192;
            f32x4 sfr[4] = {};
            __builtin_amdgcn_s_setprio(1);
#pragma unroll
            for (int kt = 0; kt < 4; kt++) {
                const int key = kt * 16 + lc;
#pragma unroll
                for (int ks = 0; ks < 4; ks++) {
                    short8 bf = *(const short8*)&Kb[key * 128 + (((ks * 4 + lg) ^ (key & 7)) << 3)];
                    sfr[kt] = __builtin_amdgcn_mfma_f32_16x16x32_bf16(aq[ks], bf, sfr[kt], 0, 0, 0);
                }
            }
            __builtin_amdgcn_s_setprio(0);
            float base[4][4];
#pragma unroll
            for (int kt = 0; kt < 4; kt++)
#pragma unroll
                for (int r = 0; r < 4; r++) base[kt][r] = sfr[kt][r] * SCALE_;

            // shared deferred max (THR=8)
            float lmax[4];
#pragma unroll
            for (int r = 0; r < 4; r++)
                lmax[r] = fmaxf(fmaxf(base[0][r], base[1][r]), fmaxf(base[2][r], base[3][r]));
            bool need = false;
#pragma unroll
            for (int r = 0; r < 4; r++) need |= (lmax[r] > m[r] + 8.f);
            if (__any(need)) {
#pragma unroll
                for (int r = 0; r < 4; r++) {
                    float rm = lmax[r];
#pragma unroll
                    for (int o = 1; o < 16; o <<= 1) rm = fmaxf(rm, __shfl_xor(rm, o));
                    const float mn = fmaxf(m[r], rm);
                    const float scf = __expf(m[r] - mn);
                    m[r] = mn;
#pragma unroll
                    for (int j = 0; j < 8; j++) { acc_s[j][r] *= scf; acc_w[j][r] *= scf; }
                    ls4[r] *= scf;
                    lw4[r] *= scf;
                }
            }
            float e[4][4];
#pragma unroll
            for (int kt = 0; kt < 4; kt++)
#pragma unroll
                for (int r = 0; r < 4; r++) e[kt][r] = __expf(base[kt][r] - m[r]);

            // ---- build + write both P tiles ----
            if (slc_w) {
                float ps[4][4];
                if (jb < cur) {
                    float mr[4];
#pragma unroll
                    for (int r = 0; r < 4; r++) mr[r] = (float)((amr[r] >> jb) & 1u);
#pragma unroll
                    for (int kt = 0; kt < 4; kt++)
#pragma unroll
                        for (int r = 0; r < 4; r++) ps[kt][r] = e[kt][r] * mr[r];
                } else {
#pragma unroll
                    for (int kt = 0; kt < 4; kt++) {
                        const int kpos = jb * 64 + kt * 16 + lc;
#pragma unroll
                        for (int r = 0; r < 4; r++) {
                            const bool ok = (kpos <= tq[r]) && ((amr[r] >> jb) & 1u);
                            ps[kt][r] = ok ? e[kt][r] : 0.f;
                        }
                    }
                }
                write_P(Ps[w][0], ps, lc, lg);
            }
            if (swa_w) {
                const bool fullwin = (jb < cur) && (jb * 64 > tmax_w - WIN_);
                if (fullwin) {
                    write_P(Ps[w][1], e, lc, lg);
                } else {
                    float pw[4][4];
#pragma unroll
                    for (int kt = 0; kt < 4; kt++) {
                        const int kpos = jb * 64 + kt * 16 + lc;
#pragma unroll
                        for (int r = 0; r < 4; r++) {
                            const bool ok = (kpos <= tq[r]) && (kpos > tq[r] - WIN_);
                            pw[kt][r] = ok ? e[kt][r] : 0.f;
                        }
                    }
                    write_P(Ps[w][1], pw, lc, lg);
                }
            }

            // ---- merged PV: each V fragment read once ----
            __builtin_amdgcn_s_setprio(1);
#pragma unroll
            for (int ks2 = 0; ks2 < 2; ks2++) {
                short8 afs = {}, afw = {};
                if (slc_w) {
                    afs = *(const short8*)&Ps[w][0][lc * 64 + ((ks2 * 32 + lg * 8) ^ ((lc & 7) << 3))];
                    ls4 = __builtin_amdgcn_mfma_f32_16x16x32_bf16(afs, ones, ls4, 0, 0, 0);
                }
                if (swa_w) {
                    afw = *(const short8*)&Ps[w][1][lc * 64 + ((ks2 * 32 + lg * 8) ^ ((lc & 7) << 3))];
                    lw4 = __builtin_amdgcn_mfma_f32_16x16x32_bf16(afw, ones, lw4, 0, 0, 0);
                }
#pragma unroll
                for (int nj = 0; nj < 8; nj++) {
                    const int dd = nj * 16 + lc;
                    short8 bf = *(const short8*)&Vb[dd * 64 + (((ks2 * 4 + lg) ^ (dd & 7)) << 3)];
                    if (slc_w) acc_s[nj] = __builtin_amdgcn_mfma_f32_16x16x32_bf16(afs, bf, acc_s[nj], 0, 0, 0);
                    if (swa_w) acc_w[nj] = __builtin_amdgcn_mfma_f32_16x16x32_bf16(afw, bf, acc_w[nj], 0, 0, 0);
                }
            }
            __builtin_amdgcn_s_setprio(0);
        }
        __syncthreads();   // all waves done with KV before next overwrite
    }

    // epilogue: write partials (shared m for both streams)
    const size_t base2 = (size_t)(qb * 16 + h) * 2 + seg;
    if (lc == 0) {
#pragma unroll
        for (int r = 0; r < 4; r++) {
            const int row = w * 16 + lg * 4 + r;
            float4v v;
            v[0] = m[r]; v[1] = ls4[r]; v[2] = m[r]; v[3] = lw4[r];
            *(float4v*)&mlp[(base2 * 64 + row) * 4] = v;
        }
    }
#pragma unroll
    for (int st = 0; st < 2; st++) {
        const f32x4* A = st ? acc_w : acc_s;
#pragma unroll
        for (int nj = 0; nj < 8; nj++)
#pragma unroll
            for (int r = 0; r < 4; r++) {
                const int row = w * 16 + lg * 4 + r;
                accp[((base2 * 2 + st) * 64 + row) * 128 + nj * 16 + lc] = f2b(A[nj][r]);
            }
    }
}

// ---------------------------------------------------------------------------
// Combine segments + gating + obuf add -> bf16 o
// ---------------------------------------------------------------------------
__global__ __launch_bounds__(256) void slc_comb(const float* __restrict__ obuf,
                                                const float* __restrict__ mlp,
                                                const unsigned short* __restrict__ accp,
                                                const float* __restrict__ gate,
                                                const float* __restrict__ sinks,
                                                unsigned short* __restrict__ obufb) {
    const int t = blockIdx.x;
    const int qb = t >> 6, row = t & 63;
    const int tid = threadIdx.x;
    const int d = tid & 127, half = tid >> 7;
    const float g1 = gate[t * 3 + 1], g2 = gate[t * 3 + 2];
#pragma unroll
    for (int hh = 0; hh < 8; hh++) {
        const int h = half * 8 + hh;
        const size_t base2 = (size_t)(qb * 16 + h) * 2;
        const float4v ml0 = *(const float4v*)&mlp[((base2 + 0) * 64 + row) * 4];
        const float4v ml1 = *(const float4v*)&mlp[((base2 + 1) * 64 + row) * 4];
        const float Ms = fmaxf(ml0[0], ml1[0]);
        const float e0 = __expf(ml0[0] - Ms), e1 = __expf(ml1[0] - Ms);
        const float ls = ml0[1] * e0 + ml1[1] * e1;
        const float a0 = b2f(accp[(((base2 + 0) * 2 + 0) * 64 + row) * 128 + d]);
        const float a1 = b2f(accp[(((base2 + 1) * 2 + 0) * 64 + row) * 128 + d]);
        const float os = (a0 * e0 + a1 * e1) / ls;
        const float snk = sinks[h];
        const float Mw = fmaxf(fmaxf(ml0[2], ml1[2]), snk);
        const float w0 = __expf(ml0[2] - Mw), w1 = __expf(ml1[2] - Mw);
        const float den = ml0[3] * w0 + ml1[3] * w1 + __expf(snk - Mw);
        const float b0 = b2f(accp[(((base2 + 0) * 2 + 1) * 64 + row) * 128 + d]);
        const float b1 = b2f(accp[(((base2 + 1) * 2 + 1) * 64 + row) * 128 + d]);
        const float ow = (b0 * w0 + b1 * w1) / den;
        const size_t idx = (size_t)t * (H_ * D_) + h * D_ + d;
        obufb[idx] = f2b(obuf[idx] + g1 * os + g2 * ow);
    }
}

// ---------------------------------------------------------------------------
extern "C" void kernel_launch(void* const* d_in, const int* in_sizes, int n_in,
                              void* d_out, int out_size, void* d_ws, size_t ws_size,
                              hipStream_t stream) {
    const float* x = (const float*)d_in[0];
    const float* W_qkv = (const float*)d_in[1];
    const float* b_qkv = (const float*)d_in[2];
    const float* W_out = (const float*)d_in[3];
    const float* b_out = (const float*)d_in[4];
    const float* sinks = (const float*)d_in[5];
    const float* cmp_pos = (const float*)d_in[6];
    const float* W_c1 = (const float*)d_in[7];
    const float* b_c1 = (const float*)d_in[8];
    const float* W_c2 = (const float*)d_in[9];
    const float* b_c2 = (const float*)d_in[10];
    const float* W_g1 = (const float*)d_in[11];
    const float* b_g1 = (const float*)d_in[12];
    const float* W_g2 = (const float*)d_in[13];
    const float* b_g2 = (const float*)d_in[14];

    char* ws = (char*)d_ws;
    unsigned short* qkvb = (unsigned short*)(ws + 0);
    unsigned short* obufb = (unsigned short*)(ws + 0);
    char* A0 = ws + 12582912;
    unsigned short* Wqkv_b = (unsigned short*)(A0);
    unsigned short* blkb = (unsigned short*)(A0);
    float* obuf = (float*)(A0);
    char* B0 = ws + 29360128;
    unsigned short* x_b = (unsigned short*)(B0);
    unsigned short* kvTs = (unsigned short*)(B0);
    float* gateb = (float*)(ws + 37748736);                    // 24,576
    unsigned int* amaskb = (unsigned int*)(ws + 37773312);     // 8,192
    float* scg = (float*)(ws + 37781504);                      // 1M -> 38,830,080
    float* mlp = (float*)(ws + 38830080);                      // 1M -> 39,878,656
    unsigned short* accp = (unsigned short*)(ws + 39878656);
    unsigned short* Wg1_b = (unsigned short*)(ws + 39878656);  // 2M
    unsigned short* Wc1_b = (unsigned short*)(ws + 41975808);  // 2M
    unsigned short* Wc2_b = (unsigned short*)(ws + 44072960);  // 64K
    float* hgate = (float*)(ws + 44138496);                    // 4M
    unsigned short* hc_b = (unsigned short*)(ws + 48332800);   // 1M
    unsigned short* hcmpb = (unsigned short*)(ws + 49381376);  // 512K
    unsigned short* vcmpT = (unsigned short*)(ws + 49905664);  // 128K
    float* c1part = (float*)(ws + 50036736);                   // 8.39M -> 58,425,344
    unsigned short* Wout_b = (unsigned short*)(ws + 39878656); // after slc_comb
    float* outf = (float*)d_out;

    // 1) fused bf16 conversions
    cvt_all<<<dim3(12320), 256, 0, stream>>>(x, W_qkv, W_g1, W_c1, W_c2,
                                             x_b, Wqkv_b, Wg1_b, Wc1_b, Wc2_b);
    // 2) fused qkv + gate-hidden GEMM (64x128 tile, 896 blocks)
    gemm_qkvg<<<dim3((QKV_N + GATE_HID_) / 128, T_ / 64), 256, 0, stream>>>(
        x_b, Wqkv_b, Wg1_b, b_qkv, b_g1, qkvb, hgate);
    // 3) fused: K+V pre-swizzled tiles | gates | compression inputs (x_b dead)
    post_qkv<<<dim3(3712), 256, 0, stream>>>(qkvb, cmp_pos, hgate, W_g2, b_g2,
                                             kvTs, gateb, blkb);
    // 4) compression layer 1, split-K=4 (64x128 tile, 256 blocks)
    gemm_c1p<<<dim3(2, 32, 4), 256, 0, stream>>>(blkb, Wc1_b, c1part);
    c1_red<<<dim3(512), 256, 0, stream>>>(c1part, b_c1, hc_b);
    // 5) compression layer 2 (64x128 tile, 32 blocks, + transposed V emit)
    gemm_c2<<<dim3(1, 32), 256, 0, stream>>>(hc_b, Wc2_b, b_c2, hcmpb, vcmpT);
    // 6) CMP attention + block-score slices; obuf = g0*o_cmp
    cmp_attn2<<<dim3(512), 256, 0, stream>>>(qkvb, hcmpb, vcmpT, gateb, obuf, scg);
    // 7) top-k -> mask
    topk_k<<<dim3(T_ / 256), 256, 0, stream>>>(scg, amaskb);
    // 8) SLC+SWA partials (v9: merged PV, single-buffered KV, 48KB LDS)
    slc_swa_pt<<<dim3(1024), 256, 0, stream>>>(qkvb, kvTs, amaskb, mlp, accp);
    // 9) combine + gating -> bf16 o (qkvb dead; obufb at ws+0)
    slc_comb<<<dim3(T_), 256, 0, stream>>>(obuf, mlp, accp, gateb, sinks, obufb);
    // 10) W_out to bf16 (accp dead)
    cvt_f2b<<<dim3(4096), 256, 0, stream>>>(W_out, Wout_b, DIM_ * H_ * D_);
    // 11) out = o @ W_out^T + b_out (64x128 tile, 512 blocks)
    gemm64<0, true, false><<<dim3(DIM_ / 128, T_ / 64), 256, 0, stream>>>(
        obufb, Wout_b, b_out, outf, nullptr, T_, DIM_, H_ * D_);
}

// Round 14
// 260.874 us; speedup vs baseline: 1.0549x; 1.0549x over previous
//
#include <hip/hip_runtime.h>
#include <hip/hip_bf16.h>

#define DEV static __device__ __forceinline__

constexpr int T_ = 2048, DIM_ = 2048, H_ = 16, KVH = 4, D_ = 128;
constexpr int LL = 32, SS = 16, TOPK_ = 16, WIN_ = 512;
constexpr int GATE_HID_ = 512;
constexpr int TC_ = 127, NS_ = 32;
constexpr int QKV_N = (H_ + 2 * KVH) * D_;          // 3072
constexpr float SCALE_ = 0.08838834764831845f;       // D^-0.5

typedef __attribute__((ext_vector_type(8))) short short8;
typedef __attribute__((ext_vector_type(4))) float f32x4;
typedef __attribute__((ext_vector_type(4))) float float4v;
typedef __attribute__((ext_vector_type(4))) unsigned short u16x4;

DEV unsigned short f2b(float x) {
    return __builtin_bit_cast(unsigned short, __float2bfloat16(x));
}
DEV float b2f(unsigned short u) { return __builtin_bit_cast(float, ((unsigned)u) << 16); }
DEV float gelu_f(float x) { return 0.5f * x * (1.f + erff(x * 0.70710678118654752f)); }

DEV void g2l16(const void* g, void* l) {
    __builtin_amdgcn_global_load_lds((const __attribute__((address_space(1))) unsigned int*)g,
                                     (__attribute__((address_space(3))) unsigned int*)l, 16, 0, 0);
}

// ---------------------------------------------------------------------------
// f32 -> bf16 conversion (vectorized), n divisible by 4
// ---------------------------------------------------------------------------
__global__ void cvt_f2b(const float* __restrict__ s, unsigned short* __restrict__ d, int n) {
    const int i = (blockIdx.x * 256 + threadIdx.x) * 4;
    if (i >= n) return;
    float4v v = *(const float4v*)(s + i);
    u16x4 o;
#pragma unroll
    for (int j = 0; j < 4; j++) o[j] = f2b(v[j]);
    *(u16x4*)(d + i) = o;
}

// ---------------------------------------------------------------------------
// Fused conversion of x, W_qkv, W_g1, W_c1, W_c2 (one launch)
// ---------------------------------------------------------------------------
__global__ void cvt_all(const float* __restrict__ x, const float* __restrict__ wq,
                        const float* __restrict__ wg, const float* __restrict__ wc1,
                        const float* __restrict__ wc2,
                        unsigned short* __restrict__ xb, unsigned short* __restrict__ wqb,
                        unsigned short* __restrict__ wgb, unsigned short* __restrict__ wc1b,
                        unsigned short* __restrict__ wc2b) {
    const long i = ((long)blockIdx.x * 256 + threadIdx.x) * 4;
    const float* s;
    unsigned short* d;
    long off;
    if (i < 4194304)        { s = x;   d = xb;   off = i; }
    else if (i < 10485760)  { s = wq;  d = wqb;  off = i - 4194304; }
    else if (i < 11534336)  { s = wg;  d = wgb;  off = i - 10485760; }
    else if (i < 12582912)  { s = wc1; d = wc1b; off = i - 11534336; }
    else if (i < 12615680)  { s = wc2; d = wc2b; off = i - 12582912; }
    else return;
    float4v v = *(const float4v*)(s + off);
    u16x4 o;
#pragma unroll
    for (int j = 0; j < 4; j++) o[j] = f2b(v[j]);
    *(u16x4*)(d + off) = o;
}

// ---------------------------------------------------------------------------
// BK=64 GEMM building blocks: swizzled g2l16 staging + matching ds_read XOR.
// ---------------------------------------------------------------------------
DEV void stage64(const unsigned short* __restrict__ src, unsigned short* dstL,
                 int K, int tid) {        // 128 rows
#pragma unroll
    for (int it = 0; it < 4; it++) {
        const int e = it * 256 + tid;          // 16B-chunk index, 0..1023
        const int row = e >> 3, cg = e & 7;
        g2l16(src + (size_t)row * K + ((cg ^ (row & 7)) << 3), dstL + e * 8);
    }
}
DEV void stageA64(const unsigned short* __restrict__ src, unsigned short* dstL,
                  int K, int tid) {       // 64 rows
#pragma unroll
    for (int it = 0; it < 2; it++) {
        const int e = it * 256 + tid;          // 0..511
        const int row = e >> 3, cg = e & 7;
        g2l16(src + (size_t)row * K + ((cg ^ (row & 7)) << 3), dstL + e * 8);
    }
}
DEV short8 frag64(const unsigned short* Ls, int row, int g) {   // g = ks*4+lg
    return *(const short8*)&Ls[row * 64 + ((g ^ (row & 7)) << 3)];
}

// ---------------------------------------------------------------------------
// bf16 GEMM, 64x128 tile (BK=64): C = A @ B^T + bias. More blocks/CU.
// Wave w covers cols w*32..w*32+31; acc[4][2].
// ---------------------------------------------------------------------------
template <int ACT, bool WF, bool WB>
__global__ __launch_bounds__(256) void gemm64(const unsigned short* __restrict__ A,
                                              const unsigned short* __restrict__ B,
                                              const float* __restrict__ bias,
                                              float* __restrict__ Cf,
                                              unsigned short* __restrict__ Cb,
                                              int M, int N, int K) {
    __shared__ __align__(16) unsigned short As[64 * 64];
    __shared__ __align__(16) unsigned short Bs[128 * 64];
    const int tid = threadIdx.x;
    const int w = tid >> 6, l = tid & 63;
    const int lc = l & 15, lg = l >> 4;
    const int m0 = blockIdx.y * 64, n0 = blockIdx.x * 128;
    f32x4 acc[4][2] = {};
    for (int k0 = 0; k0 < K; k0 += 64) {
        stageA64(A + (size_t)m0 * K + k0, As, K, tid);
        stage64(B + (size_t)n0 * K + k0, Bs, K, tid);
        __syncthreads();
#pragma unroll
        for (int ks = 0; ks < 2; ks++) {
            short8 af[4], bfr[2];
#pragma unroll
            for (int mi = 0; mi < 4; mi++) af[mi] = frag64(As, mi * 16 + lc, ks * 4 + lg);
#pragma unroll
            for (int ni = 0; ni < 2; ni++) bfr[ni] = frag64(Bs, w * 32 + ni * 16 + lc, ks * 4 + lg);
#pragma unroll
            for (int mi = 0; mi < 4; mi++)
#pragma unroll
                for (int ni = 0; ni < 2; ni++)
                    acc[mi][ni] = __builtin_amdgcn_mfma_f32_16x16x32_bf16(af[mi], bfr[ni], acc[mi][ni], 0, 0, 0);
        }
        __syncthreads();
    }
#pragma unroll
    for (int mi = 0; mi < 4; mi++) {
        const int gr = m0 + mi * 16 + lg * 4;
#pragma unroll
        for (int ni = 0; ni < 2; ni++) {
            const int gc = n0 + w * 32 + ni * 16 + lc;
            const float bv = bias[gc];
#pragma unroll
            for (int r = 0; r < 4; r++) {
                float v = acc[mi][ni][r] + bv;
                if (ACT == 1) v = gelu_f(v);
                const size_t idx = (size_t)(gr + r) * N + gc;
                if (WF) Cf[idx] = v;
                if (WB) Cb[idx] = f2b(v);
            }
        }
    }
}

// ---------------------------------------------------------------------------
// Fused qkv + gate-hidden GEMM, 64x128 tile
// ---------------------------------------------------------------------------
__global__ __launch_bounds__(256) void gemm_qkvg(const unsigned short* __restrict__ A,
                                                 const unsigned short* __restrict__ Bq,
                                                 const unsigned short* __restrict__ Bg,
                                                 const float* __restrict__ bq,
                                                 const float* __restrict__ bg,
                                                 unsigned short* __restrict__ Cq,
                                                 float* __restrict__ Cg) {
    __shared__ __align__(16) unsigned short As[64 * 64];
    __shared__ __align__(16) unsigned short Bs[128 * 64];
    const int K = DIM_;
    const int tid = threadIdx.x;
    const int w = tid >> 6, l = tid & 63;
    const int lc = l & 15, lg = l >> 4;
    const int m0 = blockIdx.y * 64, n0 = blockIdx.x * 128;
    const bool isg = (n0 >= QKV_N);
    const unsigned short* B = isg ? (Bg + (size_t)(n0 - QKV_N) * K) : (Bq + (size_t)n0 * K);
    f32x4 acc[4][2] = {};
    for (int k0 = 0; k0 < K; k0 += 64) {
        stageA64(A + (size_t)m0 * K + k0, As, K, tid);
        stage64(B + k0, Bs, K, tid);
        __syncthreads();
#pragma unroll
        for (int ks = 0; ks < 2; ks++) {
            short8 af[4], bfr[2];
#pragma unroll
            for (int mi = 0; mi < 4; mi++) af[mi] = frag64(As, mi * 16 + lc, ks * 4 + lg);
#pragma unroll
            for (int ni = 0; ni < 2; ni++) bfr[ni] = frag64(Bs, w * 32 + ni * 16 + lc, ks * 4 + lg);
#pragma unroll
            for (int mi = 0; mi < 4; mi++)
#pragma unroll
                for (int ni = 0; ni < 2; ni++)
                    acc[mi][ni] = __builtin_amdgcn_mfma_f32_16x16x32_bf16(af[mi], bfr[ni], acc[mi][ni], 0, 0, 0);
        }
        __syncthreads();
    }
#pragma unroll
    for (int mi = 0; mi < 4; mi++) {
        const int gr = m0 + mi * 16 + lg * 4;
#pragma unroll
        for (int ni = 0; ni < 2; ni++) {
            const int gcl = (n0 - (isg ? QKV_N : 0)) + w * 32 + ni * 16 + lc;
            const float bv = isg ? bg[gcl] : bq[gcl];
#pragma unroll
            for (int r = 0; r < 4; r++) {
                const float v = acc[mi][ni][r] + bv;
                if (isg) Cg[(size_t)(gr + r) * GATE_HID_ + gcl] = gelu_f(v);
                else Cq[(size_t)(gr + r) * QKV_N + gcl] = f2b(v);
            }
        }
    }
}

// ---------------------------------------------------------------------------
// c1 GEMM, split-K partials, 64x128 tile
// ---------------------------------------------------------------------------
__global__ __launch_bounds__(256) void gemm_c1p(const unsigned short* __restrict__ A,
                                                const unsigned short* __restrict__ B,
                                                float* __restrict__ part) {
    __shared__ __align__(16) unsigned short As[64 * 64];
    __shared__ __align__(16) unsigned short Bs[128 * 64];
    const int K = 4096, N = 256;
    const int tid = threadIdx.x;
    const int w = tid >> 6, l = tid & 63;
    const int lc = l & 15, lg = l >> 4;
    const int m0 = blockIdx.y * 64, n0 = blockIdx.x * 128;
    const int kz = blockIdx.z * 1024;
    f32x4 acc[4][2] = {};
    for (int k0 = kz; k0 < kz + 1024; k0 += 64) {
        stageA64(A + (size_t)m0 * K + k0, As, K, tid);
        stage64(B + (size_t)n0 * K + k0, Bs, K, tid);
        __syncthreads();
#pragma unroll
        for (int ks = 0; ks < 2; ks++) {
            short8 af[4], bfr[2];
#pragma unroll
            for (int mi = 0; mi < 4; mi++) af[mi] = frag64(As, mi * 16 + lc, ks * 4 + lg);
#pragma unroll
            for (int ni = 0; ni < 2; ni++) bfr[ni] = frag64(Bs, w * 32 + ni * 16 + lc, ks * 4 + lg);
#pragma unroll
            for (int mi = 0; mi < 4; mi++)
#pragma unroll
                for (int ni = 0; ni < 2; ni++)
                    acc[mi][ni] = __builtin_amdgcn_mfma_f32_16x16x32_bf16(af[mi], bfr[ni], acc[mi][ni], 0, 0, 0);
        }
        __syncthreads();
    }
    float* dst = part + (size_t)blockIdx.z * 2048 * 256;
#pragma unroll
    for (int mi = 0; mi < 4; mi++) {
        const int gr = m0 + mi * 16 + lg * 4;
#pragma unroll
        for (int ni = 0; ni < 2; ni++) {
            const int gc = n0 + w * 32 + ni * 16 + lc;
#pragma unroll
            for (int r = 0; r < 4; r++) dst[(size_t)(gr + r) * N + gc] = acc[mi][ni][r];
        }
    }
}

// ---------------------------------------------------------------------------
// reduce c1 partials + bias + gelu -> bf16
// ---------------------------------------------------------------------------
__global__ void c1_red(const float* __restrict__ part, const float* __restrict__ bias,
                       unsigned short* __restrict__ out) {
    const int i4 = blockIdx.x * 256 + threadIdx.x;   // 131072
    const int base = i4 * 4;
    const int col = base & 255;
    float4v v = *(const float4v*)(part + base);
#pragma unroll
    for (int z = 1; z < 4; z++) {
        float4v p = *(const float4v*)(part + (size_t)z * 524288 + base);
#pragma unroll
        for (int j = 0; j < 4; j++) v[j] += p[j];
    }
    u16x4 o;
#pragma unroll
    for (int j = 0; j < 4; j++) o[j] = f2b(gelu_f(v[j] + bias[col + j]));
    *(u16x4*)(out + base) = o;
}

// ---------------------------------------------------------------------------
// c2 GEMM, 64x128 tile: hcmp = hc @ Wc2^T + b; also emits vcmpT[kv][d][c]
// ---------------------------------------------------------------------------
__global__ __launch_bounds__(256) void gemm_c2(const unsigned short* __restrict__ A,
                                               const unsigned short* __restrict__ B,
                                               const float* __restrict__ bias,
                                               unsigned short* __restrict__ Cb,
                                               unsigned short* __restrict__ vcmpT) {
    __shared__ __align__(16) unsigned short As[64 * 64];
    __shared__ __align__(16) unsigned short Bs[128 * 64];
    const int K = 256, N = 128;
    const int tid = threadIdx.x;
    const int w = tid >> 6, l = tid & 63;
    const int lc = l & 15, lg = l >> 4;
    const int m0 = blockIdx.y * 64;
    f32x4 acc[4][2] = {};
    for (int k0 = 0; k0 < K; k0 += 64) {
        stageA64(A + (size_t)m0 * K + k0, As, K, tid);
        stage64(B + k0, Bs, K, tid);
        __syncthreads();
#pragma unroll
        for (int ks = 0; ks < 2; ks++) {
            short8 af[4], bfr[2];
#pragma unroll
            for (int mi = 0; mi < 4; mi++) af[mi] = frag64(As, mi * 16 + lc, ks * 4 + lg);
#pragma unroll
            for (int ni = 0; ni < 2; ni++) bfr[ni] = frag64(Bs, w * 32 + ni * 16 + lc, ks * 4 + lg);
#pragma unroll
            for (int mi = 0; mi < 4; mi++)
#pragma unroll
                for (int ni = 0; ni < 2; ni++)
                    acc[mi][ni] = __builtin_amdgcn_mfma_f32_16x16x32_bf16(af[mi], bfr[ni], acc[mi][ni], 0, 0, 0);
        }
        __syncthreads();
    }
#pragma unroll
    for (int mi = 0; mi < 4; mi++) {
        const int gr = m0 + mi * 16 + lg * 4;
#pragma unroll
        for (int ni = 0; ni < 2; ni++) {
            const int gc = w * 32 + ni * 16 + lc;
            const float bv = bias[gc];
#pragma unroll
            for (int r = 0; r < 4; r++) {
                const int row = gr + r;
                const float v = acc[mi][ni][r] + bv;
                const unsigned short bv16 = f2b(v);
                Cb[(size_t)row * N + gc] = bv16;
                if (row >= 1024) {
                    const int mm = row - 1024;
                    const int cc = mm >> 2, kvv = mm & 3;
                    if (cc < 128) vcmpT[((size_t)(kvv * 128 + gc)) * 128 + cc] = bv16;
                }
            }
        }
    }
}

// ---------------------------------------------------------------------------
// Fused post-qkv kernel: [0,128) transp_kv | [128,1664) gate2 | [1664,3712) blk_build
// ---------------------------------------------------------------------------
__global__ __launch_bounds__(256) void post_qkv(const unsigned short* __restrict__ qkvb,
                                                const float* __restrict__ cmp_pos,
                                                const float* __restrict__ hg,
                                                const float* __restrict__ Wg2,
                                                const float* __restrict__ bg2,
                                                unsigned short* __restrict__ kvTs,
                                                float* __restrict__ gate,
                                                unsigned short* __restrict__ blk) {
    const int bb = blockIdx.x;
    const int tid = threadIdx.x;
    if (bb < 128) {
        const int kv = bb & 3, tb = bb >> 2;
        const int t0 = tb * 64;
        unsigned short* dstK = kvTs + (size_t)(kv * 32 + tb) * 16384;
        unsigned short* dstV = dstK + 8192;
        const int kcol0 = H_ * D_ + kv * D_;
        const int vcol0 = H_ * D_ + KVH * D_ + kv * D_;
#pragma unroll
        for (int it = 0; it < 4; it++) {
            const int c = it * 256 + tid;
            const int key = c >> 4, g = c & 15;
            short8 v = *(const short8*)(qkvb + (size_t)(t0 + key) * QKV_N + kcol0 + g * 8);
            *(short8*)(dstK + key * 128 + ((g ^ (key & 7)) << 3)) = v;
        }
        __shared__ __align__(16) unsigned short tile[64][136];
        const int rr = tid >> 4, d0 = (tid & 15) * 8;
#pragma unroll
        for (int mIt = 0; mIt < 4; mIt++) {
            const int row = rr + mIt * 16;
            *(short8*)&tile[row][d0] = *(const short8*)(qkvb + (size_t)(t0 + row) * QKV_N + vcol0 + d0);
        }
        __syncthreads();
        const int d = tid >> 1, half = tid & 1;
        unsigned short* dv = dstV + d * 64;
#pragma unroll
        for (int c2 = 0; c2 < 4; c2++) {
            const int g = half * 4 + c2;
            short8 v;
#pragma unroll
            for (int j = 0; j < 8; j++) v[j] = tile[g * 8 + j][d];
            *(short8*)(dv + ((g ^ (d & 7)) << 3)) = v;
        }
    } else if (bb < 1664) {
        const int gi = (bb - 128) * 4 + (tid >> 6);
        const int t = gi / 3, i = gi % 3;
        const int l = tid & 63;
        const float* h = hg + (size_t)t * GATE_HID_;
        const float* w = Wg2 + (size_t)i * GATE_HID_;
        float s = 0.f;
#pragma unroll
        for (int j = 0; j < GATE_HID_ / 64; j++) s += h[l + j * 64] * w[l + j * 64];
#pragma unroll
        for (int o = 32; o > 0; o >>= 1) s += __shfl_xor(s, o);
        if (l == 0) gate[gi] = 1.f / (1.f + expf(-(s + bg2[i])));
    } else {
        const int b = bb - 1664;                 // 0..2047
        const int which = b >> 10, m = b & 1023;
        unsigned short* dst = blk + ((size_t)(which * 1024 + m)) * (LL * D_);
        if (m >= TC_ * KVH) {
            short8 z = {};
#pragma unroll
            for (int it = 0; it < 2; it++) *(short8*)(dst + (tid + it * 256) * 8) = z;
            return;
        }
        const int c = m >> 2, kv = m & 3;
        const int col0 = H_ * D_ + which * KVH * D_ + kv * D_;
#pragma unroll
        for (int it = 0; it < 2; it++) {
            const int g = tid + it * 256;
            const int lrow = g >> 4, d0 = (g & 15) * 8;
            short8 z = *(const short8*)(qkvb + (size_t)(c * SS + lrow) * QKV_N + col0 + d0);
            float4v p0 = *(const float4v*)(cmp_pos + lrow * 128 + d0);
            float4v p1 = *(const float4v*)(cmp_pos + lrow * 128 + d0 + 4);
            short8 o;
#pragma unroll
            for (int j = 0; j < 4; j++) o[j] = (short)f2b(b2f((unsigned short)z[j]) + p0[j]);
#pragma unroll
            for (int j = 0; j < 4; j++) o[4 + j] = (short)f2b(b2f((unsigned short)z[4 + j]) + p1[j]);
            *(short8*)(dst + g * 8) = o;
        }
    }
}

// ---------------------------------------------------------------------------
// CMP attention (MFMA) + block-score slices; V^T direct from L2 (vcmpT)
// ---------------------------------------------------------------------------
__global__ __launch_bounds__(256) void cmp_attn2(const unsigned short* __restrict__ qkvb,
                                                 const unsigned short* __restrict__ kcmpb,
                                                 const unsigned short* __restrict__ vcmpT,
                                                 const float* __restrict__ gate,
                                                 float* __restrict__ obuf,
                                                 float* __restrict__ scg) {
    const int bid = blockIdx.x;               // 512 blocks
    const int kv = bid & 3;
    const int tx = bid >> 2;                  // 0..127
    const int tt = (tx & 1) ? (tx >> 1) : (127 - (tx >> 1));
    const int t0 = tt * 16;
    const int tid = threadIdx.x;
    const int w = tid >> 6, l = tid & 63;
    const int lc = l & 15, lg = l >> 4;
    const int h = kv * 4 + w;

    __shared__ float pbuf[4][16][132];

    short8 aq[4];
    {
        const unsigned short* qp = qkvb + (size_t)(t0 + lc) * QKV_N + h * D_ + lg * 8;
#pragma unroll
        for (int ks = 0; ks < 4; ks++) aq[ks] = *(const short8*)(qp + ks * 32);
    }

    f32x4 sfr[8] = {};
#pragma unroll
    for (int nj = 0; nj < 8; nj++) {
        const int c = nj * 16 + lc;
        const unsigned short* kp = kcmpb + ((size_t)(c * 4 + kv)) * D_ + lg * 8;
#pragma unroll
        for (int ks = 0; ks < 4; ks++) {
            short8 bf = *(const short8*)(kp + ks * 32);
            sfr[nj] = __builtin_amdgcn_mfma_f32_16x16x32_bf16(aq[ks], bf, sfr[nj], 0, 0, 0);
        }
    }

#pragma unroll
    for (int r = 0; r < 4; r++) {
        const int t = t0 + lg * 4 + r;
        const int nv = (t >= LL - 1) ? ((t - (LL - 1)) >> 4) + 1 : 0;
        float lv[8], mx = -1e30f;
#pragma unroll
        for (int nj = 0; nj < 8; nj++) {
            const int c = nj * 16 + lc;
            const float v = (c < nv) ? sfr[nj][r] * SCALE_ : -1e30f;
            lv[nj] = v;
            mx = fmaxf(mx, v);
        }
#pragma unroll
        for (int o = 1; o < 16; o <<= 1) mx = fmaxf(mx, __shfl_xor(mx, o));
        float s = 0.f, pe[8];
#pragma unroll
        for (int nj = 0; nj < 8; nj++) {
            const float e = (lv[nj] > -1e29f) ? __expf(lv[nj] - mx) : 0.f;
            pe[nj] = e;
            s += e;
        }
#pragma unroll
        for (int o = 1; o < 16; o <<= 1) s += __shfl_xor(s, o);
        const float inv = (s > 0.f) ? 1.f / s : 0.f;
#pragma unroll
        for (int nj = 0; nj < 8; nj++) sfr[nj][r] = pe[nj] * inv;
    }

#pragma unroll
    for (int nj = 0; nj < 8; nj++)
#pragma unroll
        for (int r = 0; r < 4; r++) pbuf[w][lg * 4 + r][nj * 16 + lc] = sfr[nj][r];

    __syncthreads();

    for (int idx = tid; idx < 16 * NS_; idx += 256) {
        const int lt = idx >> 5, j = idx & 31;
        int clo = 4 * j - 1;
        if (clo < 0) clo = 0;
        const int chi = 4 * j + 3;
        float s = 0.f;
        for (int c = clo; c <= chi; c++)
            s += pbuf[0][lt][c] + pbuf[1][lt][c] + pbuf[2][lt][c] + pbuf[3][lt][c];
        scg[((size_t)kv * T_ + (t0 + lt)) * NS_ + j] = s;
    }

    short8 pa[4];
#pragma unroll
    for (int ks = 0; ks < 4; ks++) {
        const float* pr = &pbuf[w][lc][ks * 32 + lg * 8];
        short8 t;
#pragma unroll
        for (int j = 0; j < 8; j++) t[j] = (short)f2b(pr[j]);
        pa[ks] = t;
    }
    f32x4 acc[8] = {};
#pragma unroll
    for (int nj = 0; nj < 8; nj++) {
        const int dd = nj * 16 + lc;
        const unsigned short* vp = vcmpT + ((size_t)(kv * 128 + dd)) * 128 + lg * 8;
#pragma unroll
        for (int ks = 0; ks < 4; ks++) {
            short8 bf = *(const short8*)(vp + ks * 32);
            acc[nj] = __builtin_amdgcn_mfma_f32_16x16x32_bf16(pa[ks], bf, acc[nj], 0, 0, 0);
        }
    }

#pragma unroll
    for (int r = 0; r < 4; r++) {
        const int t = t0 + lg * 4 + r;
        const float g0 = gate[t * 3 + 0];
#pragma unroll
        for (int nj = 0; nj < 8; nj++)
            obuf[(size_t)t * (H_ * D_) + h * D_ + nj * 16 + lc] = g0 * acc[nj][r];
    }
}

// ---------------------------------------------------------------------------
// top-k block selection -> bitmask
// ---------------------------------------------------------------------------
__global__ __launch_bounds__(256) void topk_k(const float* __restrict__ scg,
                                              unsigned int* __restrict__ amask) {
    const int t = blockIdx.x * 256 + threadIdx.x;
    if (t >= T_) return;
    float sc[NS_];
#pragma unroll
    for (int j = 0; j < NS_; j++)
        sc[j] = scg[((size_t)0 * T_ + t) * NS_ + j] + scg[((size_t)1 * T_ + t) * NS_ + j] +
                scg[((size_t)2 * T_ + t) * NS_ + j] + scg[((size_t)3 * T_ + t) * NS_ + j];
    const int cur = t >> 6;
    unsigned int chosen = 0;
    for (int it = 0; it < TOPK_ - 3; it++) {
        float best = 0.f;
        int bj = -1;
        for (int j = 0; j < NS_; j++) {
            if ((chosen >> j) & 1u) continue;
            const float v = (j >= cur) ? -INFINITY : sc[j];
            if (bj < 0 || v > best) { best = v; bj = j; }
        }
        chosen |= 1u << bj;
    }
    int f1 = cur - 2; if (f1 < 0) f1 = 0;
    int f2 = cur - 1; if (f2 < 0) f2 = 0;
    chosen |= 1u | (1u << f1) | (1u << f2) | (1u << cur);
    amask[t] = chosen;
}

// ---------------------------------------------------------------------------
// helpers for slc_swa_pt
// ---------------------------------------------------------------------------
DEV void write_P(unsigned short* PsW, const float p[4][4], int lc, int lg) {
#pragma unroll
    for (int kt = 0; kt < 4; kt++) {
        const int col = kt * 16 + lc;
#pragma unroll
        for (int rp = 0; rp < 4; rp += 2) {
            unsigned int pk;
            asm("v_cvt_pk_bf16_f32 %0, %1, %2" : "=v"(pk) : "v"(p[kt][rp]), "v"(p[kt][rp + 1]));
            const int row0 = lg * 4 + rp;
            const int row1 = row0 + 1;
            PsW[row0 * 64 + (col ^ ((row0 & 7) << 3))] = (unsigned short)(pk & 0xFFFFu);
            PsW[row1 * 64 + (col ^ ((row1 & 7) << 3))] = (unsigned short)(pk >> 16);
        }
    }
}

DEV void stageKV(const unsigned short* __restrict__ src, unsigned short* dst, int tid) {
#pragma unroll
    for (int it = 0; it < 8; it++) {
        const int c = it * 256 + tid;          // 16B chunk index, 0..2047
        g2l16(src + c * 8, dst + c * 8);
    }
}

// ---------------------------------------------------------------------------
// SLC+SWA partial kernel v8: single-buffered KV (40KB LDS), 1024 blocks
// (one qb each, heaviest first) -> 4 scheduled vs 3 resident per CU, backfill.
// ---------------------------------------------------------------------------
__global__ __launch_bounds__(256) void slc_swa_pt(const unsigned short* __restrict__ qkvb,
                                                  const unsigned short* __restrict__ kvTs,
                                                  const unsigned int* __restrict__ amask,
                                                  float* __restrict__ mlp,
                                                  unsigned short* __restrict__ accp) {
    const int bid = blockIdx.x;               // 1024 blocks
    const int qb = 31 - (bid >> 5);           // heaviest first
    const int hs = bid & 31;
    const int h = hs >> 1, seg = hs & 1;
    const int kv = h >> 2;
    const int tid = threadIdx.x;
    const int w = tid >> 6, l = tid & 63;
    const int lc = l & 15, lg = l >> 4;
    const int t0 = qb * 64;
    const int cur = qb;

    __shared__ __align__(16) unsigned short KV[16384];   // [K 8192 | V 8192]
    __shared__ __align__(16) unsigned short Ps[4][1024];

    const short8 ones = {0x3F80, 0x3F80, 0x3F80, 0x3F80, 0x3F80, 0x3F80, 0x3F80, 0x3F80};

    // masks fully in registers
    const unsigned int aml = amask[t0 + l];
    unsigned int u64v = aml;
#pragma unroll
    for (int o = 1; o < 64; o <<= 1) u64v |= __shfl_xor(u64v, o);
    unsigned int u16g = aml;
#pragma unroll
    for (int o = 1; o < 16; o <<= 1) u16g |= __shfl_xor(u16g, o);
    const unsigned int uni16 = __shfl(u16g, w * 16);
    unsigned int amr[4];
    int tq[4];
#pragma unroll
    for (int r = 0; r < 4; r++) {
        const int rl = w * 16 + lg * 4 + r;
        tq[r] = t0 + rl;
        amr[r] = __shfl(aml, rl);
    }
    const int tmin_w = t0 + w * 16;
    const int tmax_w = tmin_w + 15;

    const unsigned int curm = (cur >= 31) ? 0xFFFFFFFFu : ((1u << (cur + 1)) - 1u);
    int sl = qb - 8; if (sl < 0) sl = 0;
    const unsigned int swab = curm & ~((1u << sl) - 1u);
    const unsigned int act = (u64v & curm) | swab;
    unsigned int actseg = 0;
    {
        int rank = 0;
        for (int jb = 0; jb <= cur; jb++)
            if ((act >> jb) & 1u) {
                if ((rank & 1) == seg) actseg |= 1u << jb;
                rank++;
            }
    }

    short8 aq[4];
    {
        const unsigned short* qp = qkvb + (size_t)(t0 + w * 16 + lc) * QKV_N + h * D_ + lg * 8;
#pragma unroll
        for (int ks = 0; ks < 4; ks++) aq[ks] = *(const short8*)(qp + ks * 32);
    }

    f32x4 acc_s[8] = {};
    f32x4 acc_w[8] = {};
    f32x4 ls4 = {}, lw4 = {};
    float m[4];
#pragma unroll
    for (int r = 0; r < 4; r++) m[r] = -1e30f;

    const unsigned short* kvbase = kvTs + (size_t)kv * 32 * 16384;

    unsigned int rem = actseg;
    while (rem) {
        const int jb = __ffs(rem) - 1;
        rem &= rem - 1;
        stageKV(kvbase + (size_t)jb * 16384, KV, tid);
        __syncthreads();   // KV(jb) staged
        const bool slc_w = (uni16 >> jb) & 1u;
        const bool swa_w = (jb * 64 + 63) > (tmin_w - WIN_);
        if (slc_w || swa_w) {
            const unsigned short* Kb = KV;
            const unsigned short* Vb = KV + 8192;
            f32x4 sfr[4] = {};
            __builtin_amdgcn_s_setprio(1);
#pragma unroll
            for (int kt = 0; kt < 4; kt++) {
                const int key = kt * 16 + lc;
#pragma unroll
                for (int ks = 0; ks < 4; ks++) {
                    short8 bf = *(const short8*)&Kb[key * 128 + (((ks * 4 + lg) ^ (key & 7)) << 3)];
                    sfr[kt] = __builtin_amdgcn_mfma_f32_16x16x32_bf16(aq[ks], bf, sfr[kt], 0, 0, 0);
                }
            }
            __builtin_amdgcn_s_setprio(0);
            float base[4][4];
#pragma unroll
            for (int kt = 0; kt < 4; kt++)
#pragma unroll
                for (int r = 0; r < 4; r++) base[kt][r] = sfr[kt][r] * SCALE_;

            // shared deferred max (THR=8)
            float lmax[4];
#pragma unroll
            for (int r = 0; r < 4; r++)
                lmax[r] = fmaxf(fmaxf(base[0][r], base[1][r]), fmaxf(base[2][r], base[3][r]));
            bool need = false;
#pragma unroll
            for (int r = 0; r < 4; r++) need |= (lmax[r] > m[r] + 8.f);
            if (__any(need)) {
#pragma unroll
                for (int r = 0; r < 4; r++) {
                    float rm = lmax[r];
#pragma unroll
                    for (int o = 1; o < 16; o <<= 1) rm = fmaxf(rm, __shfl_xor(rm, o));
                    const float mn = fmaxf(m[r], rm);
                    const float scf = __expf(m[r] - mn);
                    m[r] = mn;
#pragma unroll
                    for (int j = 0; j < 8; j++) { acc_s[j][r] *= scf; acc_w[j][r] *= scf; }
                    ls4[r] *= scf;
                    lw4[r] *= scf;
                }
            }
            float e[4][4];
#pragma unroll
            for (int kt = 0; kt < 4; kt++)
#pragma unroll
                for (int r = 0; r < 4; r++) e[kt][r] = __expf(base[kt][r] - m[r]);

            if (slc_w) {
                float ps[4][4];
                if (jb < cur) {
                    float mr[4];
#pragma unroll
                    for (int r = 0; r < 4; r++) mr[r] = (float)((amr[r] >> jb) & 1u);
#pragma unroll
                    for (int kt = 0; kt < 4; kt++)
#pragma unroll
                        for (int r = 0; r < 4; r++) ps[kt][r] = e[kt][r] * mr[r];
                } else {
#pragma unroll
                    for (int kt = 0; kt < 4; kt++) {
                        const int kpos = jb * 64 + kt * 16 + lc;
#pragma unroll
                        for (int r = 0; r < 4; r++) {
                            const bool ok = (kpos <= tq[r]) && ((amr[r] >> jb) & 1u);
                            ps[kt][r] = ok ? e[kt][r] : 0.f;
                        }
                    }
                }
                write_P(Ps[w], ps, lc, lg);
                __builtin_amdgcn_s_setprio(1);
#pragma unroll
                for (int ks2 = 0; ks2 < 2; ks2++) {
                    short8 af = *(const short8*)&Ps[w][lc * 64 + ((ks2 * 32 + lg * 8) ^ ((lc & 7) << 3))];
                    ls4 = __builtin_amdgcn_mfma_f32_16x16x32_bf16(af, ones, ls4, 0, 0, 0);
#pragma unroll
                    for (int nj = 0; nj < 8; nj++) {
                        const int dd = nj * 16 + lc;
                        short8 bf = *(const short8*)&Vb[dd * 64 + (((ks2 * 4 + lg) ^ (dd & 7)) << 3)];
                        acc_s[nj] = __builtin_amdgcn_mfma_f32_16x16x32_bf16(af, bf, acc_s[nj], 0, 0, 0);
                    }
                }
                __builtin_amdgcn_s_setprio(0);
            }
            if (swa_w) {
                const bool fullwin = (jb < cur) && (jb * 64 > tmax_w - WIN_);
                if (fullwin) {
                    write_P(Ps[w], e, lc, lg);
                } else {
                    float pw[4][4];
#pragma unroll
                    for (int kt = 0; kt < 4; kt++) {
                        const int kpos = jb * 64 + kt * 16 + lc;
#pragma unroll
                        for (int r = 0; r < 4; r++) {
                            const bool ok = (kpos <= tq[r]) && (kpos > tq[r] - WIN_);
                            pw[kt][r] = ok ? e[kt][r] : 0.f;
                        }
                    }
                    write_P(Ps[w], pw, lc, lg);
                }
                __builtin_amdgcn_s_setprio(1);
#pragma unroll
                for (int ks2 = 0; ks2 < 2; ks2++) {
                    short8 af = *(const short8*)&Ps[w][lc * 64 + ((ks2 * 32 + lg * 8) ^ ((lc & 7) << 3))];
                    lw4 = __builtin_amdgcn_mfma_f32_16x16x32_bf16(af, ones, lw4, 0, 0, 0);
#pragma unroll
                    for (int nj = 0; nj < 8; nj++) {
                        const int dd = nj * 16 + lc;
                        short8 bf = *(const short8*)&Vb[dd * 64 + (((ks2 * 4 + lg) ^ (dd & 7)) << 3)];
                        acc_w[nj] = __builtin_amdgcn_mfma_f32_16x16x32_bf16(af, bf, acc_w[nj], 0, 0, 0);
                    }
                }
                __builtin_amdgcn_s_setprio(0);
            }
        }
        __syncthreads();   // all waves done with KV before next overwrite
    }

    // epilogue: write partials (shared m for both streams)
    const size_t base2 = (size_t)(qb * 16 + h) * 2 + seg;
    if (lc == 0) {
#pragma unroll
        for (int r = 0; r < 4; r++) {
            const int row = w * 16 + lg * 4 + r;
            float4v v;
            v[0] = m[r]; v[1] = ls4[r]; v[2] = m[r]; v[3] = lw4[r];
            *(float4v*)&mlp[(base2 * 64 + row) * 4] = v;
        }
    }
#pragma unroll
    for (int st = 0; st < 2; st++) {
        const f32x4* A = st ? acc_w : acc_s;
#pragma unroll
        for (int nj = 0; nj < 8; nj++)
#pragma unroll
            for (int r = 0; r < 4; r++) {
                const int row = w * 16 + lg * 4 + r;
                accp[((base2 * 2 + st) * 64 + row) * 128 + nj * 16 + lc] = f2b(A[nj][r]);
            }
    }
}

// ---------------------------------------------------------------------------
// Combine segments + gating + obuf add -> bf16 o
// ---------------------------------------------------------------------------
__global__ __launch_bounds__(256) void slc_comb(const float* __restrict__ obuf,
                                                const float* __restrict__ mlp,
                                                const unsigned short* __restrict__ accp,
                                                const float* __restrict__ gate,
                                                const float* __restrict__ sinks,
                                                unsigned short* __restrict__ obufb) {
    const int t = blockIdx.x;
    const int qb = t >> 6, row = t & 63;
    const int tid = threadIdx.x;
    const int d = tid & 127, half = tid >> 7;
    const float g1 = gate[t * 3 + 1], g2 = gate[t * 3 + 2];
#pragma unroll
    for (int hh = 0; hh < 8; hh++) {
        const int h = half * 8 + hh;
        const size_t base2 = (size_t)(qb * 16 + h) * 2;
        const float4v ml0 = *(const float4v*)&mlp[((base2 + 0) * 64 + row) * 4];
        const float4v ml1 = *(const float4v*)&mlp[((base2 + 1) * 64 + row) * 4];
        const float Ms = fmaxf(ml0[0], ml1[0]);
        const float e0 = __expf(ml0[0] - Ms), e1 = __expf(ml1[0] - Ms);
        const float ls = ml0[1] * e0 + ml1[1] * e1;
        const float a0 = b2f(accp[(((base2 + 0) * 2 + 0) * 64 + row) * 128 + d]);
        const float a1 = b2f(accp[(((base2 + 1) * 2 + 0) * 64 + row) * 128 + d]);
        const float os = (a0 * e0 + a1 * e1) / ls;
        const float snk = sinks[h];
        const float Mw = fmaxf(fmaxf(ml0[2], ml1[2]), snk);
        const float w0 = __expf(ml0[2] - Mw), w1 = __expf(ml1[2] - Mw);
        const float den = ml0[3] * w0 + ml1[3] * w1 + __expf(snk - Mw);
        const float b0 = b2f(accp[(((base2 + 0) * 2 + 1) * 64 + row) * 128 + d]);
        const float b1 = b2f(accp[(((base2 + 1) * 2 + 1) * 64 + row) * 128 + d]);
        const float ow = (b0 * w0 + b1 * w1) / den;
        const size_t idx = (size_t)t * (H_ * D_) + h * D_ + d;
        obufb[idx] = f2b(obuf[idx] + g1 * os + g2 * ow);
    }
}

// ---------------------------------------------------------------------------
extern "C" void kernel_launch(void* const* d_in, const int* in_sizes, int n_in,
                              void* d_out, int out_size, void* d_ws, size_t ws_size,
                              hipStream_t stream) {
    const float* x = (const float*)d_in[0];
    const float* W_qkv = (const float*)d_in[1];
    const float* b_qkv = (const float*)d_in[2];
    const float* W_out = (const float*)d_in[3];
    const float* b_out = (const float*)d_in[4];
    const float* sinks = (const float*)d_in[5];
    const float* cmp_pos = (const float*)d_in[6];
    const float* W_c1 = (const float*)d_in[7];
    const float* b_c1 = (const float*)d_in[8];
    const float* W_c2 = (const float*)d_in[9];
    const float* b_c2 = (const float*)d_in[10];
    const float* W_g1 = (const float*)d_in[11];
    const float* b_g1 = (const float*)d_in[12];
    const float* W_g2 = (const float*)d_in[13];
    const float* b_g2 = (const float*)d_in[14];

    char* ws = (char*)d_ws;
    unsigned short* qkvb = (unsigned short*)(ws + 0);
    unsigned short* obufb = (unsigned short*)(ws + 0);
    char* A0 = ws + 12582912;
    unsigned short* Wqkv_b = (unsigned short*)(A0);
    unsigned short* blkb = (unsigned short*)(A0);
    float* obuf = (float*)(A0);
    char* B0 = ws + 29360128;
    unsigned short* x_b = (unsigned short*)(B0);
    unsigned short* kvTs = (unsigned short*)(B0);
    float* gateb = (float*)(ws + 37748736);                    // 24,576
    unsigned int* amaskb = (unsigned int*)(ws + 37773312);     // 8,192
    float* scg = (float*)(ws + 37781504);                      // 1M -> 38,830,080
    float* mlp = (float*)(ws + 38830080);                      // 1M -> 39,878,656
    unsigned short* accp = (unsigned short*)(ws + 39878656);
    unsigned short* Wg1_b = (unsigned short*)(ws + 39878656);  // 2M
    unsigned short* Wc1_b = (unsigned short*)(ws + 41975808);  // 2M
    unsigned short* Wc2_b = (unsigned short*)(ws + 44072960);  // 64K
    float* hgate = (float*)(ws + 44138496);                    // 4M
    unsigned short* hc_b = (unsigned short*)(ws + 48332800);   // 1M
    unsigned short* hcmpb = (unsigned short*)(ws + 49381376);  // 512K
    unsigned short* vcmpT = (unsigned short*)(ws + 49905664);  // 128K
    float* c1part = (float*)(ws + 50036736);                   // 8.39M -> 58,425,344
    unsigned short* Wout_b = (unsigned short*)(ws + 39878656); // after slc_comb
    float* outf = (float*)d_out;

    // 1) fused bf16 conversions
    cvt_all<<<dim3(12320), 256, 0, stream>>>(x, W_qkv, W_g1, W_c1, W_c2,
                                             x_b, Wqkv_b, Wg1_b, Wc1_b, Wc2_b);
    // 2) fused qkv + gate-hidden GEMM (64x128 tile, 896 blocks)
    gemm_qkvg<<<dim3((QKV_N + GATE_HID_) / 128, T_ / 64), 256, 0, stream>>>(
        x_b, Wqkv_b, Wg1_b, b_qkv, b_g1, qkvb, hgate);
    // 3) fused: K+V pre-swizzled tiles | gates | compression inputs (x_b dead)
    post_qkv<<<dim3(3712), 256, 0, stream>>>(qkvb, cmp_pos, hgate, W_g2, b_g2,
                                             kvTs, gateb, blkb);
    // 4) compression layer 1, split-K=4 (64x128 tile, 256 blocks)
    gemm_c1p<<<dim3(2, 32, 4), 256, 0, stream>>>(blkb, Wc1_b, c1part);
    c1_red<<<dim3(512), 256, 0, stream>>>(c1part, b_c1, hc_b);
    // 5) compression layer 2 (64x128 tile, 32 blocks, + transposed V emit)
    gemm_c2<<<dim3(1, 32), 256, 0, stream>>>(hc_b, Wc2_b, b_c2, hcmpb, vcmpT);
    // 6) CMP attention + block-score slices; obuf = g0*o_cmp
    cmp_attn2<<<dim3(512), 256, 0, stream>>>(qkvb, hcmpb, vcmpT, gateb, obuf, scg);
    // 7) top-k -> mask
    topk_k<<<dim3(T_ / 256), 256, 0, stream>>>(scg, amaskb);
    // 8) SLC+SWA partials (v8: 1024 blocks, single-buffered KV)
    slc_swa_pt<<<dim3(1024), 256, 0, stream>>>(qkvb, kvTs, amaskb, mlp, accp);
    // 9) combine + gating -> bf16 o (qkvb dead; obufb at ws+0)
    slc_comb<<<dim3(T_), 256, 0, stream>>>(obuf, mlp, accp, gateb, sinks, obufb);
    // 10) W_out to bf16 (accp dead)
    cvt_f2b<<<dim3(4096), 256, 0, stream>>>(W_out, Wout_b, DIM_ * H_ * D_);
    // 11) out = o @ W_out^T + b_out (64x128 tile, 512 blocks)
    gemm64<0, true, false><<<dim3(DIM_ / 128, T_ / 64), 256, 0, stream>>>(
        obufb, Wout_b, b_out, outf, nullptr, T_, DIM_, H_ * D_);
}

// Round 15
// 258.550 us; speedup vs baseline: 1.0643x; 1.0090x over previous
//
#include <hip/hip_runtime.h>
#include <hip/hip_bf16.h>

#define DEV static __device__ __forceinline__

constexpr int T_ = 2048, DIM_ = 2048, H_ = 16, KVH = 4, D_ = 128;
constexpr int LL = 32, SS = 16, TOPK_ = 16, WIN_ = 512;
constexpr int GATE_HID_ = 512;
constexpr int TC_ = 127, NS_ = 32;
constexpr int QKV_N = (H_ + 2 * KVH) * D_;          // 3072
constexpr float SCALE_ = 0.08838834764831845f;       // D^-0.5

typedef __attribute__((ext_vector_type(8))) short short8;
typedef __attribute__((ext_vector_type(4))) float f32x4;
typedef __attribute__((ext_vector_type(4))) float float4v;
typedef __attribute__((ext_vector_type(4))) unsigned short u16x4;

DEV unsigned short f2b(float x) {
    return __builtin_bit_cast(unsigned short, __float2bfloat16(x));
}
DEV float b2f(unsigned short u) { return __builtin_bit_cast(float, ((unsigned)u) << 16); }
DEV float gelu_f(float x) { return 0.5f * x * (1.f + erff(x * 0.70710678118654752f)); }

DEV void g2l16(const void* g, void* l) {
    __builtin_amdgcn_global_load_lds((const __attribute__((address_space(1))) unsigned int*)g,
                                     (__attribute__((address_space(3))) unsigned int*)l, 16, 0, 0);
}

// ---------------------------------------------------------------------------
// f32 -> bf16 conversion (vectorized), n divisible by 4
// ---------------------------------------------------------------------------
__global__ void cvt_f2b(const float* __restrict__ s, unsigned short* __restrict__ d, int n) {
    const int i = (blockIdx.x * 256 + threadIdx.x) * 4;
    if (i >= n) return;
    float4v v = *(const float4v*)(s + i);
    u16x4 o;
#pragma unroll
    for (int j = 0; j < 4; j++) o[j] = f2b(v[j]);
    *(u16x4*)(d + i) = o;
}

// ---------------------------------------------------------------------------
// Fused conversion of x, W_qkv, W_g1, W_c1, W_c2 (+ optional W_out) in one launch
// ---------------------------------------------------------------------------
__global__ void cvt_all(const float* __restrict__ x, const float* __restrict__ wq,
                        const float* __restrict__ wg, const float* __restrict__ wc1,
                        const float* __restrict__ wc2, const float* __restrict__ wo,
                        unsigned short* __restrict__ xb, unsigned short* __restrict__ wqb,
                        unsigned short* __restrict__ wgb, unsigned short* __restrict__ wc1b,
                        unsigned short* __restrict__ wc2b, unsigned short* __restrict__ wob) {
    const long i = ((long)blockIdx.x * 256 + threadIdx.x) * 4;
    const float* s;
    unsigned short* d;
    long off;
    if (i < 4194304)        { s = x;   d = xb;   off = i; }
    else if (i < 10485760)  { s = wq;  d = wqb;  off = i - 4194304; }
    else if (i < 11534336)  { s = wg;  d = wgb;  off = i - 10485760; }
    else if (i < 12582912)  { s = wc1; d = wc1b; off = i - 11534336; }
    else if (i < 12615680)  { s = wc2; d = wc2b; off = i - 12582912; }
    else if (i < 16809984)  { if (wob == nullptr) return; s = wo; d = wob; off = i - 12615680; }
    else return;
    float4v v = *(const float4v*)(s + off);
    u16x4 o;
#pragma unroll
    for (int j = 0; j < 4; j++) o[j] = f2b(v[j]);
    *(u16x4*)(d + off) = o;
}

// ---------------------------------------------------------------------------
// BK=64 GEMM building blocks: swizzled g2l16 staging + matching ds_read XOR.
// ---------------------------------------------------------------------------
DEV void stage64(const unsigned short* __restrict__ src, unsigned short* dstL,
                 int K, int tid) {        // 128 rows
#pragma unroll
    for (int it = 0; it < 4; it++) {
        const int e = it * 256 + tid;          // 16B-chunk index, 0..1023
        const int row = e >> 3, cg = e & 7;
        g2l16(src + (size_t)row * K + ((cg ^ (row & 7)) << 3), dstL + e * 8);
    }
}
DEV void stageA64(const unsigned short* __restrict__ src, unsigned short* dstL,
                  int K, int tid) {       // 64 rows
#pragma unroll
    for (int it = 0; it < 2; it++) {
        const int e = it * 256 + tid;          // 0..511
        const int row = e >> 3, cg = e & 7;
        g2l16(src + (size_t)row * K + ((cg ^ (row & 7)) << 3), dstL + e * 8);
    }
}
DEV short8 frag64(const unsigned short* Ls, int row, int g) {   // g = ks*4+lg
    return *(const short8*)&Ls[row * 64 + ((g ^ (row & 7)) << 3)];
}

// ---------------------------------------------------------------------------
// bf16 GEMM, 64x128 tile (BK=64): C = A @ B^T + bias. More blocks/CU.
// Wave w covers cols w*32..w*32+31; acc[4][2].
// ---------------------------------------------------------------------------
template <int ACT, bool WF, bool WB>
__global__ __launch_bounds__(256) void gemm64(const unsigned short* __restrict__ A,
                                              const unsigned short* __restrict__ B,
                                              const float* __restrict__ bias,
                                              float* __restrict__ Cf,
                                              unsigned short* __restrict__ Cb,
                                              int M, int N, int K) {
    __shared__ __align__(16) unsigned short As[64 * 64];
    __shared__ __align__(16) unsigned short Bs[128 * 64];
    const int tid = threadIdx.x;
    const int w = tid >> 6, l = tid & 63;
    const int lc = l & 15, lg = l >> 4;
    const int m0 = blockIdx.y * 64, n0 = blockIdx.x * 128;
    f32x4 acc[4][2] = {};
    for (int k0 = 0; k0 < K; k0 += 64) {
        stageA64(A + (size_t)m0 * K + k0, As, K, tid);
        stage64(B + (size_t)n0 * K + k0, Bs, K, tid);
        __syncthreads();
#pragma unroll
        for (int ks = 0; ks < 2; ks++) {
            short8 af[4], bfr[2];
#pragma unroll
            for (int mi = 0; mi < 4; mi++) af[mi] = frag64(As, mi * 16 + lc, ks * 4 + lg);
#pragma unroll
            for (int ni = 0; ni < 2; ni++) bfr[ni] = frag64(Bs, w * 32 + ni * 16 + lc, ks * 4 + lg);
#pragma unroll
            for (int mi = 0; mi < 4; mi++)
#pragma unroll
                for (int ni = 0; ni < 2; ni++)
                    acc[mi][ni] = __builtin_amdgcn_mfma_f32_16x16x32_bf16(af[mi], bfr[ni], acc[mi][ni], 0, 0, 0);
        }
        __syncthreads();
    }
#pragma unroll
    for (int mi = 0; mi < 4; mi++) {
        const int gr = m0 + mi * 16 + lg * 4;
#pragma unroll
        for (int ni = 0; ni < 2; ni++) {
            const int gc = n0 + w * 32 + ni * 16 + lc;
            const float bv = bias[gc];
#pragma unroll
            for (int r = 0; r < 4; r++) {
                float v = acc[mi][ni][r] + bv;
                if (ACT == 1) v = gelu_f(v);
                const size_t idx = (size_t)(gr + r) * N + gc;
                if (WF) Cf[idx] = v;
                if (WB) Cb[idx] = f2b(v);
            }
        }
    }
}

// ---------------------------------------------------------------------------
// Fused qkv + gate-hidden GEMM, 64x128 tile
// ---------------------------------------------------------------------------
__global__ __launch_bounds__(256) void gemm_qkvg(const unsigned short* __restrict__ A,
                                                 const unsigned short* __restrict__ Bq,
                                                 const unsigned short* __restrict__ Bg,
                                                 const float* __restrict__ bq,
                                                 const float* __restrict__ bg,
                                                 unsigned short* __restrict__ Cq,
                                                 float* __restrict__ Cg) {
    __shared__ __align__(16) unsigned short As[64 * 64];
    __shared__ __align__(16) unsigned short Bs[128 * 64];
    const int K = DIM_;
    const int tid = threadIdx.x;
    const int w = tid >> 6, l = tid & 63;
    const int lc = l & 15, lg = l >> 4;
    const int m0 = blockIdx.y * 64, n0 = blockIdx.x * 128;
    const bool isg = (n0 >= QKV_N);
    const unsigned short* B = isg ? (Bg + (size_t)(n0 - QKV_N) * K) : (Bq + (size_t)n0 * K);
    f32x4 acc[4][2] = {};
    for (int k0 = 0; k0 < K; k0 += 64) {
        stageA64(A + (size_t)m0 * K + k0, As, K, tid);
        stage64(B + k0, Bs, K, tid);
        __syncthreads();
#pragma unroll
        for (int ks = 0; ks < 2; ks++) {
            short8 af[4], bfr[2];
#pragma unroll
            for (int mi = 0; mi < 4; mi++) af[mi] = frag64(As, mi * 16 + lc, ks * 4 + lg);
#pragma unroll
            for (int ni = 0; ni < 2; ni++) bfr[ni] = frag64(Bs, w * 32 + ni * 16 + lc, ks * 4 + lg);
#pragma unroll
            for (int mi = 0; mi < 4; mi++)
#pragma unroll
                for (int ni = 0; ni < 2; ni++)
                    acc[mi][ni] = __builtin_amdgcn_mfma_f32_16x16x32_bf16(af[mi], bfr[ni], acc[mi][ni], 0, 0, 0);
        }
        __syncthreads();
    }
#pragma unroll
    for (int mi = 0; mi < 4; mi++) {
        const int gr = m0 + mi * 16 + lg * 4;
#pragma unroll
        for (int ni = 0; ni < 2; ni++) {
            const int gcl = (n0 - (isg ? QKV_N : 0)) + w * 32 + ni * 16 + lc;
            const float bv = isg ? bg[gcl] : bq[gcl];
#pragma unroll
            for (int r = 0; r < 4; r++) {
                const float v = acc[mi][ni][r] + bv;
                if (isg) Cg[(size_t)(gr + r) * GATE_HID_ + gcl] = gelu_f(v);
                else Cq[(size_t)(gr + r) * QKV_N + gcl] = f2b(v);
            }
        }
    }
}

// ---------------------------------------------------------------------------
// c1 GEMM, split-K partials, 64x128 tile
// ---------------------------------------------------------------------------
__global__ __launch_bounds__(256) void gemm_c1p(const unsigned short* __restrict__ A,
                                                const unsigned short* __restrict__ B,
                                                float* __restrict__ part) {
    __shared__ __align__(16) unsigned short As[64 * 64];
    __shared__ __align__(16) unsigned short Bs[128 * 64];
    const int K = 4096, N = 256;
    const int tid = threadIdx.x;
    const int w = tid >> 6, l = tid & 63;
    const int lc = l & 15, lg = l >> 4;
    const int m0 = blockIdx.y * 64, n0 = blockIdx.x * 128;
    const int kz = blockIdx.z * 1024;
    f32x4 acc[4][2] = {};
    for (int k0 = kz; k0 < kz + 1024; k0 += 64) {
        stageA64(A + (size_t)m0 * K + k0, As, K, tid);
        stage64(B + (size_t)n0 * K + k0, Bs, K, tid);
        __syncthreads();
#pragma unroll
        for (int ks = 0; ks < 2; ks++) {
            short8 af[4], bfr[2];
#pragma unroll
            for (int mi = 0; mi < 4; mi++) af[mi] = frag64(As, mi * 16 + lc, ks * 4 + lg);
#pragma unroll
            for (int ni = 0; ni < 2; ni++) bfr[ni] = frag64(Bs, w * 32 + ni * 16 + lc, ks * 4 + lg);
#pragma unroll
            for (int mi = 0; mi < 4; mi++)
#pragma unroll
                for (int ni = 0; ni < 2; ni++)
                    acc[mi][ni] = __builtin_amdgcn_mfma_f32_16x16x32_bf16(af[mi], bfr[ni], acc[mi][ni], 0, 0, 0);
        }
        __syncthreads();
    }
    float* dst = part + (size_t)blockIdx.z * 2048 * 256;
#pragma unroll
    for (int mi = 0; mi < 4; mi++) {
        const int gr = m0 + mi * 16 + lg * 4;
#pragma unroll
        for (int ni = 0; ni < 2; ni++) {
            const int gc = n0 + w * 32 + ni * 16 + lc;
#pragma unroll
            for (int r = 0; r < 4; r++) dst[(size_t)(gr + r) * N + gc] = acc[mi][ni][r];
        }
    }
}

// ---------------------------------------------------------------------------
// reduce c1 partials + bias + gelu -> bf16
// ---------------------------------------------------------------------------
__global__ void c1_red(const float* __restrict__ part, const float* __restrict__ bias,
                       unsigned short* __restrict__ out) {
    const int i4 = blockIdx.x * 256 + threadIdx.x;   // 131072
    const int base = i4 * 4;
    const int col = base & 255;
    float4v v = *(const float4v*)(part + base);
#pragma unroll
    for (int z = 1; z < 4; z++) {
        float4v p = *(const float4v*)(part + (size_t)z * 524288 + base);
#pragma unroll
        for (int j = 0; j < 4; j++) v[j] += p[j];
    }
    u16x4 o;
#pragma unroll
    for (int j = 0; j < 4; j++) o[j] = f2b(gelu_f(v[j] + bias[col + j]));
    *(u16x4*)(out + base) = o;
}

// ---------------------------------------------------------------------------
// c2 GEMM, 64x128 tile: hcmp = hc @ Wc2^T + b; also emits vcmpT[kv][d][c]
// ---------------------------------------------------------------------------
__global__ __launch_bounds__(256) void gemm_c2(const unsigned short* __restrict__ A,
                                               const unsigned short* __restrict__ B,
                                               const float* __restrict__ bias,
                                               unsigned short* __restrict__ Cb,
                                               unsigned short* __restrict__ vcmpT) {
    __shared__ __align__(16) unsigned short As[64 * 64];
    __shared__ __align__(16) unsigned short Bs[128 * 64];
    const int K = 256, N = 128;
    const int tid = threadIdx.x;
    const int w = tid >> 6, l = tid & 63;
    const int lc = l & 15, lg = l >> 4;
    const int m0 = blockIdx.y * 64;
    f32x4 acc[4][2] = {};
    for (int k0 = 0; k0 < K; k0 += 64) {
        stageA64(A + (size_t)m0 * K + k0, As, K, tid);
        stage64(B + k0, Bs, K, tid);
        __syncthreads();
#pragma unroll
        for (int ks = 0; ks < 2; ks++) {
            short8 af[4], bfr[2];
#pragma unroll
            for (int mi = 0; mi < 4; mi++) af[mi] = frag64(As, mi * 16 + lc, ks * 4 + lg);
#pragma unroll
            for (int ni = 0; ni < 2; ni++) bfr[ni] = frag64(Bs, w * 32 + ni * 16 + lc, ks * 4 + lg);
#pragma unroll
            for (int mi = 0; mi < 4; mi++)
#pragma unroll
                for (int ni = 0; ni < 2; ni++)
                    acc[mi][ni] = __builtin_amdgcn_mfma_f32_16x16x32_bf16(af[mi], bfr[ni], acc[mi][ni], 0, 0, 0);
        }
        __syncthreads();
    }
#pragma unroll
    for (int mi = 0; mi < 4; mi++) {
        const int gr = m0 + mi * 16 + lg * 4;
#pragma unroll
        for (int ni = 0; ni < 2; ni++) {
            const int gc = w * 32 + ni * 16 + lc;
            const float bv = bias[gc];
#pragma unroll
            for (int r = 0; r < 4; r++) {
                const int row = gr + r;
                const float v = acc[mi][ni][r] + bv;
                const unsigned short bv16 = f2b(v);
                Cb[(size_t)row * N + gc] = bv16;
                if (row >= 1024) {
                    const int mm = row - 1024;
                    const int cc = mm >> 2, kvv = mm & 3;
                    if (cc < 128) vcmpT[((size_t)(kvv * 128 + gc)) * 128 + cc] = bv16;
                }
            }
        }
    }
}

// ---------------------------------------------------------------------------
// Fused post-qkv kernel: [0,128) transp_kv | [128,1664) gate2 | [1664,3712) blk_build
// ---------------------------------------------------------------------------
__global__ __launch_bounds__(256) void post_qkv(const unsigned short* __restrict__ qkvb,
                                                const float* __restrict__ cmp_pos,
                                                const float* __restrict__ hg,
                                                const float* __restrict__ Wg2,
                                                const float* __restrict__ bg2,
                                                unsigned short* __restrict__ kvTs,
                                                float* __restrict__ gate,
                                                unsigned short* __restrict__ blk) {
    const int bb = blockIdx.x;
    const int tid = threadIdx.x;
    if (bb < 128) {
        const int kv = bb & 3, tb = bb >> 2;
        const int t0 = tb * 64;
        unsigned short* dstK = kvTs + (size_t)(kv * 32 + tb) * 16384;
        unsigned short* dstV = dstK + 8192;
        const int kcol0 = H_ * D_ + kv * D_;
        const int vcol0 = H_ * D_ + KVH * D_ + kv * D_;
#pragma unroll
        for (int it = 0; it < 4; it++) {
            const int c = it * 256 + tid;
            const int key = c >> 4, g = c & 15;
            short8 v = *(const short8*)(qkvb + (size_t)(t0 + key) * QKV_N + kcol0 + g * 8);
            *(short8*)(dstK + key * 128 + ((g ^ (key & 7)) << 3)) = v;
        }
        __shared__ __align__(16) unsigned short tile[64][136];
        const int rr = tid >> 4, d0 = (tid & 15) * 8;
#pragma unroll
        for (int mIt = 0; mIt < 4; mIt++) {
            const int row = rr + mIt * 16;
            *(short8*)&tile[row][d0] = *(const short8*)(qkvb + (size_t)(t0 + row) * QKV_N + vcol0 + d0);
        }
        __syncthreads();
        const int d = tid >> 1, half = tid & 1;
        unsigned short* dv = dstV + d * 64;
#pragma unroll
        for (int c2 = 0; c2 < 4; c2++) {
            const int g = half * 4 + c2;
            short8 v;
#pragma unroll
            for (int j = 0; j < 8; j++) v[j] = tile[g * 8 + j][d];
            *(short8*)(dv + ((g ^ (d & 7)) << 3)) = v;
        }
    } else if (bb < 1664) {
        const int gi = (bb - 128) * 4 + (tid >> 6);
        const int t = gi / 3, i = gi % 3;
        const int l = tid & 63;
        const float* h = hg + (size_t)t * GATE_HID_;
        const float* w = Wg2 + (size_t)i * GATE_HID_;
        float s = 0.f;
#pragma unroll
        for (int j = 0; j < GATE_HID_ / 64; j++) s += h[l + j * 64] * w[l + j * 64];
#pragma unroll
        for (int o = 32; o > 0; o >>= 1) s += __shfl_xor(s, o);
        if (l == 0) gate[gi] = 1.f / (1.f + expf(-(s + bg2[i])));
    } else {
        const int b = bb - 1664;                 // 0..2047
        const int which = b >> 10, m = b & 1023;
        unsigned short* dst = blk + ((size_t)(which * 1024 + m)) * (LL * D_);
        if (m >= TC_ * KVH) {
            short8 z = {};
#pragma unroll
            for (int it = 0; it < 2; it++) *(short8*)(dst + (tid + it * 256) * 8) = z;
            return;
        }
        const int c = m >> 2, kv = m & 3;
        const int col0 = H_ * D_ + which * KVH * D_ + kv * D_;
#pragma unroll
        for (int it = 0; it < 2; it++) {
            const int g = tid + it * 256;
            const int lrow = g >> 4, d0 = (g & 15) * 8;
            short8 z = *(const short8*)(qkvb + (size_t)(c * SS + lrow) * QKV_N + col0 + d0);
            float4v p0 = *(const float4v*)(cmp_pos + lrow * 128 + d0);
            float4v p1 = *(const float4v*)(cmp_pos + lrow * 128 + d0 + 4);
            short8 o;
#pragma unroll
            for (int j = 0; j < 4; j++) o[j] = (short)f2b(b2f((unsigned short)z[j]) + p0[j]);
#pragma unroll
            for (int j = 0; j < 4; j++) o[4 + j] = (short)f2b(b2f((unsigned short)z[4 + j]) + p1[j]);
            *(short8*)(dst + g * 8) = o;
        }
    }
}

// ---------------------------------------------------------------------------
// CMP attention (MFMA) + block-score slices; V^T direct from L2 (vcmpT)
// ---------------------------------------------------------------------------
__global__ __launch_bounds__(256) void cmp_attn2(const unsigned short* __restrict__ qkvb,
                                                 const unsigned short* __restrict__ kcmpb,
                                                 const unsigned short* __restrict__ vcmpT,
                                                 const float* __restrict__ gate,
                                                 float* __restrict__ obuf,
                                                 float* __restrict__ scg) {
    const int bid = blockIdx.x;               // 512 blocks
    const int kv = bid & 3;
    const int tx = bid >> 2;                  // 0..127
    const int tt = (tx & 1) ? (tx >> 1) : (127 - (tx >> 1));
    const int t0 = tt * 16;
    const int tid = threadIdx.x;
    const int w = tid >> 6, l = tid & 63;
    const int lc = l & 15, lg = l >> 4;
    const int h = kv * 4 + w;

    __shared__ float pbuf[4][16][132];

    short8 aq[4];
    {
        const unsigned short* qp = qkvb + (size_t)(t0 + lc) * QKV_N + h * D_ + lg * 8;
#pragma unroll
        for (int ks = 0; ks < 4; ks++) aq[ks] = *(const short8*)(qp + ks * 32);
    }

    f32x4 sfr[8] = {};
#pragma unroll
    for (int nj = 0; nj < 8; nj++) {
        const int c = nj * 16 + lc;
        const unsigned short* kp = kcmpb + ((size_t)(c * 4 + kv)) * D_ + lg * 8;
#pragma unroll
        for (int ks = 0; ks < 4; ks++) {
            short8 bf = *(const short8*)(kp + ks * 32);
            sfr[nj] = __builtin_amdgcn_mfma_f32_16x16x32_bf16(aq[ks], bf, sfr[nj], 0, 0, 0);
        }
    }

#pragma unroll
    for (int r = 0; r < 4; r++) {
        const int t = t0 + lg * 4 + r;
        const int nv = (t >= LL - 1) ? ((t - (LL - 1)) >> 4) + 1 : 0;
        float lv[8], mx = -1e30f;
#pragma unroll
        for (int nj = 0; nj < 8; nj++) {
            const int c = nj * 16 + lc;
            const float v = (c < nv) ? sfr[nj][r] * SCALE_ : -1e30f;
            lv[nj] = v;
            mx = fmaxf(mx, v);
        }
#pragma unroll
        for (int o = 1; o < 16; o <<= 1) mx = fmaxf(mx, __shfl_xor(mx, o));
        float s = 0.f, pe[8];
#pragma unroll
        for (int nj = 0; nj < 8; nj++) {
            const float e = (lv[nj] > -1e29f) ? __expf(lv[nj] - mx) : 0.f;
            pe[nj] = e;
            s += e;
        }
#pragma unroll
        for (int o = 1; o < 16; o <<= 1) s += __shfl_xor(s, o);
        const float inv = (s > 0.f) ? 1.f / s : 0.f;
#pragma unroll
        for (int nj = 0; nj < 8; nj++) sfr[nj][r] = pe[nj] * inv;
    }

#pragma unroll
    for (int nj = 0; nj < 8; nj++)
#pragma unroll
        for (int r = 0; r < 4; r++) pbuf[w][lg * 4 + r][nj * 16 + lc] = sfr[nj][r];

    __syncthreads();

    for (int idx = tid; idx < 16 * NS_; idx += 256) {
        const int lt = idx >> 5, j = idx & 31;
        int clo = 4 * j - 1;
        if (clo < 0) clo = 0;
        const int chi = 4 * j + 3;
        float s = 0.f;
        for (int c = clo; c <= chi; c++)
            s += pbuf[0][lt][c] + pbuf[1][lt][c] + pbuf[2][lt][c] + pbuf[3][lt][c];
        scg[((size_t)kv * T_ + (t0 + lt)) * NS_ + j] = s;
    }

    short8 pa[4];
#pragma unroll
    for (int ks = 0; ks < 4; ks++) {
        const float* pr = &pbuf[w][lc][ks * 32 + lg * 8];
        short8 t;
#pragma unroll
        for (int j = 0; j < 8; j++) t[j] = (short)f2b(pr[j]);
        pa[ks] = t;
    }
    f32x4 acc[8] = {};
#pragma unroll
    for (int nj = 0; nj < 8; nj++) {
        const int dd = nj * 16 + lc;
        const unsigned short* vp = vcmpT + ((size_t)(kv * 128 + dd)) * 128 + lg * 8;
#pragma unroll
        for (int ks = 0; ks < 4; ks++) {
            short8 bf = *(const short8*)(vp + ks * 32);
            acc[nj] = __builtin_amdgcn_mfma_f32_16x16x32_bf16(pa[ks], bf, acc[nj], 0, 0, 0);
        }
    }

#pragma unroll
    for (int r = 0; r < 4; r++) {
        const int t = t0 + lg * 4 + r;
        const float g0 = gate[t * 3 + 0];
#pragma unroll
        for (int nj = 0; nj < 8; nj++)
            obuf[(size_t)t * (H_ * D_) + h * D_ + nj * 16 + lc] = g0 * acc[nj][r];
    }
}

// ---------------------------------------------------------------------------
// top-k block selection -> bitmask
// ---------------------------------------------------------------------------
__global__ __launch_bounds__(256) void topk_k(const float* __restrict__ scg,
                                              unsigned int* __restrict__ amask) {
    const int t = blockIdx.x * 256 + threadIdx.x;
    if (t >= T_) return;
    float sc[NS_];
#pragma unroll
    for (int j = 0; j < NS_; j++)
        sc[j] = scg[((size_t)0 * T_ + t) * NS_ + j] + scg[((size_t)1 * T_ + t) * NS_ + j] +
                scg[((size_t)2 * T_ + t) * NS_ + j] + scg[((size_t)3 * T_ + t) * NS_ + j];
    const int cur = t >> 6;
    unsigned int chosen = 0;
    for (int it = 0; it < TOPK_ - 3; it++) {
        float best = 0.f;
        int bj = -1;
        for (int j = 0; j < NS_; j++) {
            if ((chosen >> j) & 1u) continue;
            const float v = (j >= cur) ? -INFINITY : sc[j];
            if (bj < 0 || v > best) { best = v; bj = j; }
        }
        chosen |= 1u << bj;
    }
    int f1 = cur - 2; if (f1 < 0) f1 = 0;
    int f2 = cur - 1; if (f2 < 0) f2 = 0;
    chosen |= 1u | (1u << f1) | (1u << f2) | (1u << cur);
    amask[t] = chosen;
}

// ---------------------------------------------------------------------------
// helpers for slc_swa_pt
// ---------------------------------------------------------------------------
DEV void write_P(unsigned short* PsW, const float p[4][4], int lc, int lg) {
#pragma unroll
    for (int kt = 0; kt < 4; kt++) {
        const int col = kt * 16 + lc;
#pragma unroll
        for (int rp = 0; rp < 4; rp += 2) {
            unsigned int pk;
            asm("v_cvt_pk_bf16_f32 %0, %1, %2" : "=v"(pk) : "v"(p[kt][rp]), "v"(p[kt][rp + 1]));
            const int row0 = lg * 4 + rp;
            const int row1 = row0 + 1;
            PsW[row0 * 64 + (col ^ ((row0 & 7) << 3))] = (unsigned short)(pk & 0xFFFFu);
            PsW[row1 * 64 + (col ^ ((row1 & 7) << 3))] = (unsigned short)(pk >> 16);
        }
    }
}

DEV void stageKV(const unsigned short* __restrict__ src, unsigned short* dst, int tid) {
#pragma unroll
    for (int it = 0; it < 8; it++) {
        const int c = it * 256 + tid;          // 16B chunk index, 0..2047
        g2l16(src + c * 8, dst + c * 8);
    }
}

// ---------------------------------------------------------------------------
// SLC+SWA partial kernel v8: single-buffered KV (40KB LDS), 1024 blocks
// (one qb each, heaviest first) -> 4 scheduled vs 3 resident per CU, backfill.
// ---------------------------------------------------------------------------
__global__ __launch_bounds__(256) void slc_swa_pt(const unsigned short* __restrict__ qkvb,
                                                  const unsigned short* __restrict__ kvTs,
                                                  const unsigned int* __restrict__ amask,
                                                  float* __restrict__ mlp,
                                                  unsigned short* __restrict__ accp) {
    const int bid = blockIdx.x;               // 1024 blocks
    const int qb = 31 - (bid >> 5);           // heaviest first
    const int hs = bid & 31;
    const int h = hs >> 1, seg = hs & 1;
    const int kv = h >> 2;
    const int tid = threadIdx.x;
    const int w = tid >> 6, l = tid & 63;
    const int lc = l & 15, lg = l >> 4;
    const int t0 = qb * 64;
    const int cur = qb;

    __shared__ __align__(16) unsigned short KV[16384];   // [K 8192 | V 8192]
    __shared__ __align__(16) unsigned short Ps[4][1024];

    const short8 ones = {0x3F80, 0x3F80, 0x3F80, 0x3F80, 0x3F80, 0x3F80, 0x3F80, 0x3F80};

    // masks fully in registers
    const unsigned int aml = amask[t0 + l];
    unsigned int u64v = aml;
#pragma unroll
    for (int o = 1; o < 64; o <<= 1) u64v |= __shfl_xor(u64v, o);
    unsigned int u16g = aml;
#pragma unroll
    for (int o = 1; o < 16; o <<= 1) u16g |= __shfl_xor(u16g, o);
    const unsigned int uni16 = __shfl(u16g, w * 16);
    unsigned int amr[4];
    int tq[4];
#pragma unroll
    for (int r = 0; r < 4; r++) {
        const int rl = w * 16 + lg * 4 + r;
        tq[r] = t0 + rl;
        amr[r] = __shfl(aml, rl);
    }
    const int tmin_w = t0 + w * 16;
    const int tmax_w = tmin_w + 15;

    const unsigned int curm = (cur >= 31) ? 0xFFFFFFFFu : ((1u << (cur + 1)) - 1u);
    int sl = qb - 8; if (sl < 0) sl = 0;
    const unsigned int swab = curm & ~((1u << sl) - 1u);
    const unsigned int act = (u64v & curm) | swab;
    unsigned int actseg = 0;
    {
        int rank = 0;
        for (int jb = 0; jb <= cur; jb++)
            if ((act >> jb) & 1u) {
                if ((rank & 1) == seg) actseg |= 1u << jb;
                rank++;
            }
    }

    short8 aq[4];
    {
        const unsigned short* qp = qkvb + (size_t)(t0 + w * 16 + lc) * QKV_N + h * D_ + lg * 8;
#pragma unroll
        for (int ks = 0; ks < 4; ks++) aq[ks] = *(const short8*)(qp + ks * 32);
    }

    f32x4 acc_s[8] = {};
    f32x4 acc_w[8] = {};
    f32x4 ls4 = {}, lw4 = {};
    float m[4];
#pragma unroll
    for (int r = 0; r < 4; r++) m[r] = -1e30f;

    const unsigned short* kvbase = kvTs + (size_t)kv * 32 * 16384;

    unsigned int rem = actseg;
    while (rem) {
        const int jb = __ffs(rem) - 1;
        rem &= rem - 1;
        stageKV(kvbase + (size_t)jb * 16384, KV, tid);
        __syncthreads();   // KV(jb) staged
        const bool slc_w = (uni16 >> jb) & 1u;
        const bool swa_w = (jb * 64 + 63) > (tmin_w - WIN_);
        if (slc_w || swa_w) {
            const unsigned short* Kb = KV;
            const unsigned short* Vb = KV + 8192;
            f32x4 sfr[4] = {};
            __builtin_amdgcn_s_setprio(1);
#pragma unroll
            for (int kt = 0; kt < 4; kt++) {
                const int key = kt * 16 + lc;
#pragma unroll
                for (int ks = 0; ks < 4; ks++) {
                    short8 bf = *(const short8*)&Kb[key * 128 + (((ks * 4 + lg) ^ (key & 7)) << 3)];
                    sfr[kt] = __builtin_amdgcn_mfma_f32_16x16x32_bf16(aq[ks], bf, sfr[kt], 0, 0, 0);
                }
            }
            __builtin_amdgcn_s_setprio(0);
            float base[4][4];
#pragma unroll
            for (int kt = 0; kt < 4; kt++)
#pragma unroll
                for (int r = 0; r < 4; r++) base[kt][r] = sfr[kt][r] * SCALE_;

            // shared deferred max (THR=8)
            float lmax[4];
#pragma unroll
            for (int r = 0; r < 4; r++)
                lmax[r] = fmaxf(fmaxf(base[0][r], base[1][r]), fmaxf(base[2][r], base[3][r]));
            bool need = false;
#pragma unroll
            for (int r = 0; r < 4; r++) need |= (lmax[r] > m[r] + 8.f);
            if (__any(need)) {
#pragma unroll
                for (int r = 0; r < 4; r++) {
                    float rm = lmax[r];
#pragma unroll
                    for (int o = 1; o < 16; o <<= 1) rm = fmaxf(rm, __shfl_xor(rm, o));
                    const float mn = fmaxf(m[r], rm);
                    const float scf = __expf(m[r] - mn);
                    m[r] = mn;
#pragma unroll
                    for (int j = 0; j < 8; j++) { acc_s[j][r] *= scf; acc_w[j][r] *= scf; }
                    ls4[r] *= scf;
                    lw4[r] *= scf;
                }
            }
            float e[4][4];
#pragma unroll
            for (int kt = 0; kt < 4; kt++)
#pragma unroll
                for (int r = 0; r < 4; r++) e[kt][r] = __expf(base[kt][r] - m[r]);

            if (slc_w) {
                float ps[4][4];
                if (jb < cur) {
                    float mr[4];
#pragma unroll
                    for (int r = 0; r < 4; r++) mr[r] = (float)((amr[r] >> jb) & 1u);
#pragma unroll
                    for (int kt = 0; kt < 4; kt++)
#pragma unroll
                        for (int r = 0; r < 4; r++) ps[kt][r] = e[kt][r] * mr[r];
                } else {
#pragma unroll
                    for (int kt = 0; kt < 4; kt++) {
                        const int kpos = jb * 64 + kt * 16 + lc;
#pragma unroll
                        for (int r = 0; r < 4; r++) {
                            const bool ok = (kpos <= tq[r]) && ((amr[r] >> jb) & 1u);
                            ps[kt][r] = ok ? e[kt][r] : 0.f;
                        }
                    }
                }
                write_P(Ps[w], ps, lc, lg);
                __builtin_amdgcn_s_setprio(1);
#pragma unroll
                for (int ks2 = 0; ks2 < 2; ks2++) {
                    short8 af = *(const short8*)&Ps[w][lc * 64 + ((ks2 * 32 + lg * 8) ^ ((lc & 7) << 3))];
                    ls4 = __builtin_amdgcn_mfma_f32_16x16x32_bf16(af, ones, ls4, 0, 0, 0);
#pragma unroll
                    for (int nj = 0; nj < 8; nj++) {
                        const int dd = nj * 16 + lc;
                        short8 bf = *(const short8*)&Vb[dd * 64 + (((ks2 * 4 + lg) ^ (dd & 7)) << 3)];
                        acc_s[nj] = __builtin_amdgcn_mfma_f32_16x16x32_bf16(af, bf, acc_s[nj], 0, 0, 0);
                    }
                }
                __builtin_amdgcn_s_setprio(0);
            }
            if (swa_w) {
                const bool fullwin = (jb < cur) && (jb * 64 > tmax_w - WIN_);
                if (fullwin) {
                    write_P(Ps[w], e, lc, lg);
                } else {
                    float pw[4][4];
#pragma unroll
                    for (int kt = 0; kt < 4; kt++) {
                        const int kpos = jb * 64 + kt * 16 + lc;
#pragma unroll
                        for (int r = 0; r < 4; r++) {
                            const bool ok = (kpos <= tq[r]) && (kpos > tq[r] - WIN_);
                            pw[kt][r] = ok ? e[kt][r] : 0.f;
                        }
                    }
                    write_P(Ps[w], pw, lc, lg);
                }
                __builtin_amdgcn_s_setprio(1);
#pragma unroll
                for (int ks2 = 0; ks2 < 2; ks2++) {
                    short8 af = *(const short8*)&Ps[w][lc * 64 + ((ks2 * 32 + lg * 8) ^ ((lc & 7) << 3))];
                    lw4 = __builtin_amdgcn_mfma_f32_16x16x32_bf16(af, ones, lw4, 0, 0, 0);
#pragma unroll
                    for (int nj = 0; nj < 8; nj++) {
                        const int dd = nj * 16 + lc;
                        short8 bf = *(const short8*)&Vb[dd * 64 + (((ks2 * 4 + lg) ^ (dd & 7)) << 3)];
                        acc_w[nj] = __builtin_amdgcn_mfma_f32_16x16x32_bf16(af, bf, acc_w[nj], 0, 0, 0);
                    }
                }
                __builtin_amdgcn_s_setprio(0);
            }
        }
        __syncthreads();   // all waves done with KV before next overwrite
    }

    // epilogue: write partials (shared m for both streams)
    const size_t base2 = (size_t)(qb * 16 + h) * 2 + seg;
    if (lc == 0) {
#pragma unroll
        for (int r = 0; r < 4; r++) {
            const int row = w * 16 + lg * 4 + r;
            float4v v;
            v[0] = m[r]; v[1] = ls4[r]; v[2] = m[r]; v[3] = lw4[r];
            *(float4v*)&mlp[(base2 * 64 + row) * 4] = v;
        }
    }
#pragma unroll
    for (int st = 0; st < 2; st++) {
        const f32x4* A = st ? acc_w : acc_s;
#pragma unroll
        for (int nj = 0; nj < 8; nj++)
#pragma unroll
            for (int r = 0; r < 4; r++) {
                const int row = w * 16 + lg * 4 + r;
                accp[((base2 * 2 + st) * 64 + row) * 128 + nj * 16 + lc] = f2b(A[nj][r]);
            }
    }
}

// ---------------------------------------------------------------------------
// Combine segments + gating + obuf add -> bf16 o
// ---------------------------------------------------------------------------
__global__ __launch_bounds__(256) void slc_comb(const float* __restrict__ obuf,
                                                const float* __restrict__ mlp,
                                                const unsigned short* __restrict__ accp,
                                                const float* __restrict__ gate,
                                                const float* __restrict__ sinks,
                                                unsigned short* __restrict__ obufb) {
    const int t = blockIdx.x;
    const int qb = t >> 6, row = t & 63;
    const int tid = threadIdx.x;
    const int d = tid & 127, half = tid >> 7;
    const float g1 = gate[t * 3 + 1], g2 = gate[t * 3 + 2];
#pragma unroll
    for (int hh = 0; hh < 8; hh++) {
        const int h = half * 8 + hh;
        const size_t base2 = (size_t)(qb * 16 + h) * 2;
        const float4v ml0 = *(const float4v*)&mlp[((base2 + 0) * 64 + row) * 4];
        const float4v ml1 = *(const float4v*)&mlp[((base2 + 1) * 64 + row) * 4];
        const float Ms = fmaxf(ml0[0], ml1[0]);
        const float e0 = __expf(ml0[0] - Ms), e1 = __expf(ml1[0] - Ms);
        const float ls = ml0[1] * e0 + ml1[1] * e1;
        const float a0 = b2f(accp[(((base2 + 0) * 2 + 0) * 64 + row) * 128 + d]);
        const float a1 = b2f(accp[(((base2 + 1) * 2 + 0) * 64 + row) * 128 + d]);
        const float os = (a0 * e0 + a1 * e1) / ls;
        const float snk = sinks[h];
        const float Mw = fmaxf(fmaxf(ml0[2], ml1[2]), snk);
        const float w0 = __expf(ml0[2] - Mw), w1 = __expf(ml1[2] - Mw);
        const float den = ml0[3] * w0 + ml1[3] * w1 + __expf(snk - Mw);
        const float b0 = b2f(accp[(((base2 + 0) * 2 + 1) * 64 + row) * 128 + d]);
        const float b1 = b2f(accp[(((base2 + 1) * 2 + 1) * 64 + row) * 128 + d]);
        const float ow = (b0 * w0 + b1 * w1) / den;
        const size_t idx = (size_t)t * (H_ * D_) + h * D_ + d;
        obufb[idx] = f2b(obuf[idx] + g1 * os + g2 * ow);
    }
}

// ---------------------------------------------------------------------------
extern "C" void kernel_launch(void* const* d_in, const int* in_sizes, int n_in,
                              void* d_out, int out_size, void* d_ws, size_t ws_size,
                              hipStream_t stream) {
    const float* x = (const float*)d_in[0];
    const float* W_qkv = (const float*)d_in[1];
    const float* b_qkv = (const float*)d_in[2];
    const float* W_out = (const float*)d_in[3];
    const float* b_out = (const float*)d_in[4];
    const float* sinks = (const float*)d_in[5];
    const float* cmp_pos = (const float*)d_in[6];
    const float* W_c1 = (const float*)d_in[7];
    const float* b_c1 = (const float*)d_in[8];
    const float* W_c2 = (const float*)d_in[9];
    const float* b_c2 = (const float*)d_in[10];
    const float* W_g1 = (const float*)d_in[11];
    const float* b_g1 = (const float*)d_in[12];
    const float* W_g2 = (const float*)d_in[13];
    const float* b_g2 = (const float*)d_in[14];

    char* ws = (char*)d_ws;
    unsigned short* qkvb = (unsigned short*)(ws + 0);
    unsigned short* obufb = (unsigned short*)(ws + 0);
    char* A0 = ws + 12582912;
    unsigned short* Wqkv_b = (unsigned short*)(A0);
    unsigned short* blkb = (unsigned short*)(A0);
    float* obuf = (float*)(A0);
    char* B0 = ws + 29360128;
    unsigned short* x_b = (unsigned short*)(B0);
    unsigned short* kvTs = (unsigned short*)(B0);
    float* gateb = (float*)(ws + 37748736);                    // 24,576
    unsigned int* amaskb = (unsigned int*)(ws + 37773312);     // 8,192
    float* scg = (float*)(ws + 37781504);                      // 1M -> 38,830,080
    float* mlp = (float*)(ws + 38830080);                      // 1M -> 39,878,656
    unsigned short* accp = (unsigned short*)(ws + 39878656);   // 33.55M -> 73,433,088
    unsigned short* Wg1_b = (unsigned short*)(ws + 39878656);  // 2M (pre-slc alias)
    unsigned short* Wc1_b = (unsigned short*)(ws + 41975808);  // 2M
    unsigned short* Wc2_b = (unsigned short*)(ws + 44072960);  // 64K
    float* hgate = (float*)(ws + 44138496);                    // 4M
    unsigned short* hc_b = (unsigned short*)(ws + 48332800);   // 1M
    unsigned short* hcmpb = (unsigned short*)(ws + 49381376);  // 512K
    unsigned short* vcmpT = (unsigned short*)(ws + 49905664);  // 128K
    float* c1part = (float*)(ws + 50036736);                   // 8.39M -> 58,425,344
    unsigned short* Wout_b = (unsigned short*)(ws + 39878656); // small-ws path: after slc_comb
    unsigned short* Wout_big = (unsigned short*)(ws + 73433088); // big-ws path: fresh, never aliased
    float* outf = (float*)d_out;

    const bool BIGWS = (ws_size >= 86016000ull);

    // 1) fused bf16 conversions (+ W_out when workspace allows)
    if (BIGWS) {
        cvt_all<<<dim3(16416), 256, 0, stream>>>(x, W_qkv, W_g1, W_c1, W_c2, W_out,
                                                 x_b, Wqkv_b, Wg1_b, Wc1_b, Wc2_b, Wout_big);
    } else {
        cvt_all<<<dim3(12320), 256, 0, stream>>>(x, W_qkv, W_g1, W_c1, W_c2, W_out,
                                                 x_b, Wqkv_b, Wg1_b, Wc1_b, Wc2_b, nullptr);
    }
    // 2) fused qkv + gate-hidden GEMM (64x128 tile, 896 blocks)
    gemm_qkvg<<<dim3((QKV_N + GATE_HID_) / 128, T_ / 64), 256, 0, stream>>>(
        x_b, Wqkv_b, Wg1_b, b_qkv, b_g1, qkvb, hgate);
    // 3) fused: K+V pre-swizzled tiles | gates | compression inputs (x_b dead)
    post_qkv<<<dim3(3712), 256, 0, stream>>>(qkvb, cmp_pos, hgate, W_g2, b_g2,
                                             kvTs, gateb, blkb);
    // 4) compression layer 1, split-K=4 (64x128 tile, 256 blocks)
    gemm_c1p<<<dim3(2, 32, 4), 256, 0, stream>>>(blkb, Wc1_b, c1part);
    c1_red<<<dim3(512), 256, 0, stream>>>(c1part, b_c1, hc_b);
    // 5) compression layer 2 (64x128 tile, 32 blocks, + transposed V emit)
    gemm_c2<<<dim3(1, 32), 256, 0, stream>>>(hc_b, Wc2_b, b_c2, hcmpb, vcmpT);
    // 6) CMP attention + block-score slices; obuf = g0*o_cmp
    cmp_attn2<<<dim3(512), 256, 0, stream>>>(qkvb, hcmpb, vcmpT, gateb, obuf, scg);
    // 7) top-k -> mask
    topk_k<<<dim3(T_ / 256), 256, 0, stream>>>(scg, amaskb);
    // 8) SLC+SWA partials (v8: 1024 blocks, single-buffered KV)
    slc_swa_pt<<<dim3(1024), 256, 0, stream>>>(qkvb, kvTs, amaskb, mlp, accp);
    // 9) combine + gating -> bf16 o (qkvb dead; obufb at ws+0)
    slc_comb<<<dim3(T_), 256, 0, stream>>>(obuf, mlp, accp, gateb, sinks, obufb);
    // 10) W_out to bf16 only when it couldn't be pre-converted (aliases accp, now dead)
    if (!BIGWS) cvt_f2b<<<dim3(4096), 256, 0, stream>>>(W_out, Wout_b, DIM_ * H_ * D_);
    // 11) out = o @ W_out^T + b_out (64x128 tile, 512 blocks)
    gemm64<0, true, false><<<dim3(DIM_ / 128, T_ / 64), 256, 0, stream>>>(
        obufb, BIGWS ? Wout_big : Wout_b, b_out, outf, nullptr, T_, DIM_, H_ * D_);
}